// Round 6
// baseline (3594.525 us; speedup 1.0000x reference)
//
#include <hip/hip_runtime.h>
#include <math.h>
#include <stdint.h>

#define NLAYER 6
#define DIMD 512
#define HEADS 8
#define HD 64
#define EXPERTS 8
#define SEQ 1024
#define NTOK 2048
#define FF 1024
#define VOCABN 50257
#define HROWS 50304  // 393*128 zero-padded head rows

typedef __bf16 bf16;
typedef __bf16 bf16x8 __attribute__((ext_vector_type(8)));
typedef float f32x4 __attribute__((ext_vector_type(4)));

__device__ __forceinline__ void gl_lds16(const void* g, void* l) {
  __builtin_amdgcn_global_load_lds(
      (const __attribute__((address_space(1))) void*)(uintptr_t)g,
      (__attribute__((address_space(3))) void*)(uintptr_t)l, 16, 0, 0);
}

// LDS element offset for (row, 16B-chunk) with XOR swizzle (round-5: 0 conflicts)
#define LDSW(row, kg) (((row) * 32) + ((((kg) ^ (((row) >> 1) & 3))) << 3))

// ====== pass-FUSED multi-term split-bf16 MFMA GEMM: C = A @ Bt^T ======
// A ~= sum_a A[a], B ~= sum_b B[b]; CMASK bit (a*3+b) selects combos.
// All split tiles staged once per K-step; combos are extra MFMAs on LDS data.
// PRE: 2-phase double-buffered prefetch (use only when NA+NB small).
// mLimit: per-z row count (blocks with m0>=mLimit[z] exit)
// aperm:  per-z A-row indirection [z*2048+row] (pad rows -> 2048)
template <int NA, int NB, int CMASK, bool PRE>
__global__ __launch_bounds__(256) void k_gemm(
    const bf16* __restrict__ A0, const bf16* __restrict__ A1,
    const bf16* __restrict__ A2, const bf16* __restrict__ B0,
    const bf16* __restrict__ B1, const bf16* __restrict__ B2,
    float* __restrict__ Cf, bf16* __restrict__ Cb0, bf16* __restrict__ Cb1,
    bf16* __restrict__ Cb2, int M, int N, int K,
    long sA, long sB, long sCf, long sCb,
    const float* __restrict__ colScale, int csStride,
    const float* __restrict__ bias, int biasStride,
    const float* __restrict__ residual, int act,
    const int* __restrict__ mLimit, const int* __restrict__ aperm) {
  constexpr int NBUF = PRE ? 2 : 1;
  __shared__ __align__(16) bf16 As[NBUF * NA][4096];
  __shared__ __align__(16) bf16 Bs[NBUF * NB][4096];
  int tid = threadIdx.x;
  int z = blockIdx.z;
  // bijective XCD-aware swizzle (m204)
  int nwg = gridDim.x * gridDim.y;
  int flat = blockIdx.y * gridDim.x + blockIdx.x;
  int qq = nwg >> 3, rr = nwg & 7;
  int xcd = flat & 7, ii = flat >> 3;
  int swz = (xcd < rr ? xcd * (qq + 1) : rr * (qq + 1) + (xcd - rr) * qq) + ii;
  int m0 = (swz % gridDim.x) * 128, n0 = (swz / gridDim.x) * 128;
  if (mLimit && m0 >= mLimit[z]) return;
  int w = tid >> 6, lane = tid & 63;
  int wm = (w >> 1) * 64, wn = (w & 1) * 64;
  int r15 = lane & 15, kg = lane >> 4;

  int srow = tid >> 2;
  // global source chunk pre-swizzled so linear LDS dest == swizzled layout
  int scol = (((tid & 3) ^ ((tid >> 3) & 3))) << 3;
  long arow0, arow1;
  if (aperm) {
    arow0 = aperm[z * 2048 + m0 + srow];
    arow1 = aperm[z * 2048 + m0 + 64 + srow];
  } else {
    arow0 = m0 + srow;
    arow1 = m0 + 64 + srow;
  }
  const bf16* PA[3] = {A0, A1, A2};
  const bf16* PB[3] = {B0, B1, B2};
  const bf16* aB[NA][2];
  const bf16* bB[NB][2];
#pragma unroll
  for (int a = 0; a < NA; ++a) {
    const bf16* Az = PA[a] + (long)z * sA;
    aB[a][0] = Az + arow0 * K + scol;
    aB[a][1] = Az + arow1 * K + scol;
  }
#pragma unroll
  for (int b = 0; b < NB; ++b) {
    const bf16* Bz = PB[b] + (long)z * sB;
    bB[b][0] = Bz + (long)(n0 + srow) * K + scol;
    bB[b][1] = Bz + (long)(n0 + 64 + srow) * K + scol;
  }

  f32x4 acc[4][4] = {};

  auto stage = [&](int slot, int k0) {
#pragma unroll
    for (int a = 0; a < NA; ++a) {
      gl_lds16(aB[a][0] + k0, &As[slot * NA + a][tid * 8]);
      gl_lds16(aB[a][1] + k0, &As[slot * NA + a][2048 + tid * 8]);
    }
#pragma unroll
    for (int b = 0; b < NB; ++b) {
      gl_lds16(bB[b][0] + k0, &Bs[slot * NB + b][tid * 8]);
      gl_lds16(bB[b][1] + k0, &Bs[slot * NB + b][2048 + tid * 8]);
    }
  };
  auto compute = [&](int slot) {
    bf16x8 bfr[NB][4];
#pragma unroll
    for (int b = 0; b < NB; ++b)
#pragma unroll
      for (int ni = 0; ni < 4; ++ni)
        bfr[b][ni] =
            *(const bf16x8*)&Bs[slot * NB + b][LDSW(wn + ni * 16 + r15, kg)];
#pragma unroll
    for (int a = 0; a < NA; ++a) {
      bf16x8 af[4];
#pragma unroll
      for (int mi = 0; mi < 4; ++mi)
        af[mi] =
            *(const bf16x8*)&As[slot * NA + a][LDSW(wm + mi * 16 + r15, kg)];
#pragma unroll
      for (int b = 0; b < NB; ++b) {
        if ((CMASK >> (a * 3 + b)) & 1) {
#pragma unroll
          for (int mi = 0; mi < 4; ++mi)
#pragma unroll
            for (int ni = 0; ni < 4; ++ni)
              acc[mi][ni] = __builtin_amdgcn_mfma_f32_16x16x32_bf16(
                  af[mi], bfr[b][ni], acc[mi][ni], 0, 0, 0);
        }
      }
    }
  };

  if constexpr (PRE) {
    stage(0, 0);
    __syncthreads();  // tile0 ready
    int cur = 0;
    for (int k0 = 0; k0 < K; k0 += 32) {
      if (k0 + 32 < K) stage(cur ^ 1, k0 + 32);  // issue next-tile loads
      compute(cur);                              // MFMA hides load latency
      __syncthreads();  // drains vmcnt (next tile) + readers done with cur
      cur ^= 1;
    }
  } else {
    for (int k0 = 0; k0 < K; k0 += 32) {
      stage(0, k0);
      __syncthreads();  // drains vmcnt: tiles ready
      compute(0);
      __syncthreads();  // reads done before next overwrite
    }
  }

  // C/D layout: col=lane&15, row=(lane>>4)*4+reg  [m89]
#pragma unroll
  for (int mi = 0; mi < 4; ++mi) {
    int rbase = m0 + wm + mi * 16 + kg * 4;
#pragma unroll
    for (int ni = 0; ni < 4; ++ni) {
      int col = n0 + wn + ni * 16 + r15;
      if (col >= N) continue;
      float scl = colScale ? colScale[z * csStride + col] : 1.f;
      float bv = bias ? bias[z * biasStride + col] : 0.f;
#pragma unroll
      for (int reg = 0; reg < 4; ++reg) {
        int row = rbase + reg;
        float v = acc[mi][ni][reg] * scl + bv;
        if (act) v = 0.5f * v * (1.f + erff(v * 0.70710678118654752f));
        if (residual) v += residual[(long)row * N + col];
        long ci = (long)row * N + col;
        if (Cf) Cf[z * sCf + ci] = v;
        if (Cb0) {
          bf16 h0 = (bf16)v;
          Cb0[z * sCb + ci] = h0;
          if (Cb1) {
            float r = v - (float)h0;
            bf16 h1 = (bf16)r;
            Cb1[z * sCb + ci] = h1;
            if (Cb2) Cb2[z * sCb + ci] = (bf16)(r - (float)h1);
          }
        }
      }
    }
  }
}

// ---------------- helpers ----------------
__global__ __launch_bounds__(256) void k_embed(const int* __restrict__ ids,
                                               const float* __restrict__ E,
                                               float* __restrict__ xf,
                                               bf16* __restrict__ x0,
                                               bf16* __restrict__ x1,
                                               bf16* __restrict__ x2) {
  int i = blockIdx.x * 256 + threadIdx.x;
  if (i >= NTOK * DIMD) return;
  int n = i >> 9, d = i & 511;
  float v = E[(long)ids[n] * DIMD + d];
  xf[i] = v;
  bf16 b0 = (bf16)v;
  float r = v - (float)b0;
  bf16 b1 = (bf16)r;
  x0[i] = b0; x1[i] = b1; x2[i] = (bf16)(r - (float)b1);
}

__global__ __launch_bounds__(256) void k_split3(const float* __restrict__ s,
                                                bf16* __restrict__ d0,
                                                bf16* __restrict__ d1,
                                                bf16* __restrict__ d2, long n8) {
  long i = (long)blockIdx.x * 256 + threadIdx.x;
  if (i >= n8) return;
  const float4* s4 = (const float4*)s;
  float4 a = s4[2 * i], b = s4[2 * i + 1];
  float vv[8] = {a.x, a.y, a.z, a.w, b.x, b.y, b.z, b.w};
  bf16x8 o0, o1, o2;
#pragma unroll
  for (int j = 0; j < 8; ++j) {
    float v = vv[j];
    bf16 h0 = (bf16)v;
    float r = v - (float)h0;
    bf16 h1 = (bf16)r;
    o0[j] = h0; o1[j] = h1; o2[j] = (bf16)(r - (float)h1);
  }
  ((bf16x8*)d0)[i] = o0;
  ((bf16x8*)d1)[i] = o1;
  ((bf16x8*)d2)[i] = o2;
}

__global__ __launch_bounds__(256) void k_headconv(const float* __restrict__ s,
                                                  bf16* __restrict__ d) {
  long i = (long)blockIdx.x * 256 + threadIdx.x;
  long n8 = (long)HROWS * DIMD / 8;
  if (i >= n8) return;
  long row = i / (DIMD / 8);
  bf16x8 o;
  if (row < VOCABN) {
    const float4* s4 = (const float4*)s;
    float4 a = s4[2 * i], b = s4[2 * i + 1];
    o[0] = (bf16)a.x; o[1] = (bf16)a.y; o[2] = (bf16)a.z; o[3] = (bf16)a.w;
    o[4] = (bf16)b.x; o[5] = (bf16)b.y; o[6] = (bf16)b.z; o[7] = (bf16)b.w;
  } else {
    o = (bf16x8)(bf16)0.f;
  }
  ((bf16x8*)d)[i] = o;
}

// Q,K 2-splits from f32 qkv (token layout); Q pre-scaled by 0.125 (exact)
__global__ __launch_bounds__(256) void k_qkprep(const float* __restrict__ qkv,
                                                bf16* __restrict__ q0,
                                                bf16* __restrict__ q1,
                                                bf16* __restrict__ k0,
                                                bf16* __restrict__ k1) {
  int i = blockIdx.x * 256 + threadIdx.x;  // [bh][q][d] flat
  if (i >= 16 * SEQ * HD) return;
  int d = i & 63, q = (i >> 6) & (SEQ - 1), bh = i >> 16;
  int b = bh >> 3, h = bh & 7;
  long src = ((long)(b * SEQ + q)) * (3 * DIMD) + h * HD + d;
  float qv = qkv[src] * 0.125f;
  float kv = qkv[src + DIMD];
  bf16 a = (bf16)qv; q0[i] = a; q1[i] = (bf16)(qv - (float)a);
  bf16 c = (bf16)kv; k0[i] = c; k1[i] = (bf16)(kv - (float)c);
}

// V^T 2-splits: vt[bh][d][k], rows padded to 128 per bh (pad never written)
__global__ __launch_bounds__(256) void k_vtprep(const float* __restrict__ qkv,
                                                bf16* __restrict__ vt0,
                                                bf16* __restrict__ vt1) {
  int i = blockIdx.x * 256 + threadIdx.x;  // [bh][d][k] flat
  if (i >= 16 * HD * SEQ) return;
  int k = i & (SEQ - 1), d = (i >> 10) & 63, bh = i >> 16;
  int b = bh >> 3, h = bh & 7;
  float v = qkv[((long)(b * SEQ + k)) * (3 * DIMD) + 2 * DIMD + h * HD + d];
  long dst = (long)bh * (128 * SEQ) + (long)d * SEQ + k;
  bf16 a = (bf16)v; vt0[dst] = a; vt1[dst] = (bf16)(v - (float)a);
}

// in-place row softmax on 2-split bf16 scores [16*SEQ][SEQ]
__global__ __launch_bounds__(256) void k_softmax(bf16* __restrict__ p0,
                                                 bf16* __restrict__ p1) {
  int row = blockIdx.x;
  int t = threadIdx.x;
  long base = (long)row * SEQ;
  __shared__ float red[256];
  float v[4];
  float m = -1e30f;
#pragma unroll
  for (int i = 0; i < 4; ++i) {
    long oi = base + t + i * 256;
    v[i] = (float)p0[oi] + (float)p1[oi];
    m = fmaxf(m, v[i]);
  }
  red[t] = m;
  __syncthreads();
  for (int off = 128; off; off >>= 1) {
    if (t < off) red[t] = fmaxf(red[t], red[t + off]);
    __syncthreads();
  }
  m = red[0];
  __syncthreads();
  float s = 0.f;
#pragma unroll
  for (int i = 0; i < 4; ++i) {
    v[i] = __expf(v[i] - m);
    s += v[i];
  }
  red[t] = s;
  __syncthreads();
  for (int off = 128; off; off >>= 1) {
    if (t < off) red[t] += red[t + off];
    __syncthreads();
  }
  float inv = 1.f / red[0];
#pragma unroll
  for (int i = 0; i < 4; ++i) {
    float p = v[i] * inv;
    long oi = base + t + i * 256;
    bf16 h0 = (bf16)p;
    p0[oi] = h0;
    p1[oi] = (bf16)(p - (float)h0);
  }
}

// attnf [bh][q][d] f32 -> token-layout 2-split at0/at1
__global__ __launch_bounds__(256) void k_atrepack(const float* __restrict__ attnf,
                                                  bf16* __restrict__ at0,
                                                  bf16* __restrict__ at1) {
  int i = blockIdx.x * 256 + threadIdx.x;
  if (i >= 16 * SEQ * HD) return;
  int d = i & 63, q = (i >> 6) & (SEQ - 1), bh = i >> 16;
  float v = attnf[i];
  long dst = ((long)((bh >> 3) * SEQ + q)) * DIMD + (bh & 7) * HD + d;
  bf16 a = (bf16)v;
  at0[dst] = a;
  at1[dst] = (bf16)(v - (float)a);
}

// router: top-2 expert ids + normalized weights per token
__global__ __launch_bounds__(64) void k_router(const float* __restrict__ x,
                                               const float* __restrict__ rw,
                                               const float* __restrict__ rb,
                                               int* __restrict__ top2,
                                               float* __restrict__ v2) {
  int n = blockIdx.x;
  int t = threadIdx.x;
  int e = t >> 3, part = t & 7;
  __shared__ float red[64];
  const float* xr = x + (long)n * DIMD;
  const float* wr = rw + (long)e * DIMD;
  float d = 0.f;
  int c0 = part * 64;
#pragma unroll
  for (int c = 0; c < 64; c += 4) {
    float4 xv = *(const float4*)(xr + c0 + c);
    float4 wv = *(const float4*)(wr + c0 + c);
    d += xv.x * wv.x + xv.y * wv.y + xv.z * wv.z + xv.w * wv.w;
  }
  red[t] = d;
  __syncthreads();
  if (t < 8) {
    float logit = rb[t];
    for (int pp = 0; pp < 8; ++pp) logit += red[t * 8 + pp];
    red[t] = logit;
  }
  __syncthreads();
  if (t == 0) {
    float p2[8];
    float m = -1e30f;
    for (int i = 0; i < 8; ++i) m = fmaxf(m, red[i]);
    float s = 0.f;
    for (int i = 0; i < 8; ++i) { p2[i] = expf(red[i] - m); s += p2[i]; }
    for (int i = 0; i < 8; ++i) p2[i] /= s;
    int i1 = 0;
    for (int i = 1; i < 8; ++i) if (p2[i] > p2[i1]) i1 = i;
    int i2 = (i1 == 0) ? 1 : 0;
    for (int i = 0; i < 8; ++i) {
      if (i == i1 || i == i2) continue;
      if (p2[i] > p2[i2]) i2 = i;
    }
    float sum = p2[i1] + p2[i2] + 1e-8f;
    top2[2 * n] = i1;
    top2[2 * n + 1] = i2;
    v2[2 * n] = p2[i1] / sum;
    v2[2 * n + 1] = p2[i2] / sum;
  }
}

// per-expert deterministic token lists via block prefix scan; also zeroes
// the shared zero-row (row 2048 of xB splits) used for pad rows
__global__ __launch_bounds__(256) void k_expcnt(const int* __restrict__ top2,
                                                int* __restrict__ perm,
                                                int* __restrict__ tokpos,
                                                int* __restrict__ cnt,
                                                bf16* __restrict__ zx0,
                                                bf16* __restrict__ zx1,
                                                bf16* __restrict__ zx2) {
  int e = blockIdx.x, t = threadIdx.x;
  if (e == 0) {
    for (int c = t; c < DIMD; c += 256) {
      zx0[c] = (bf16)0.f; zx1[c] = (bf16)0.f; zx2[c] = (bf16)0.f;
    }
  }
  __shared__ int sc[256];
  int base = 0;
  for (int c0 = 0; c0 < NTOK; c0 += 256) {
    int n = c0 + t;
    int f = (top2[2 * n] == e || top2[2 * n + 1] == e) ? 1 : 0;
    sc[t] = f;
    __syncthreads();
    for (int o = 1; o < 256; o <<= 1) {
      int v = (t >= o) ? sc[t - o] : 0;
      __syncthreads();
      sc[t] += v;
      __syncthreads();
    }
    if (f) {
      int pos = base + sc[t] - 1;
      perm[e * 2048 + pos] = n;
      int j = (top2[2 * n] == e) ? 0 : 1;
      tokpos[2 * n + j] = e * 2048 + pos;
    }
    base += sc[255];
    __syncthreads();
  }
  int cpad = (base + 127) & ~127;
  for (int i = base + t; i < cpad; i += 256) perm[e * 2048 + i] = 2048;
  if (t == 0) cnt[e] = base;
}

// BitNet: q in {-1,0,1} (exact bf16) + per-row f32 scale
__global__ __launch_bounds__(256) void k_bitw(const float* __restrict__ w,
                                              bf16* __restrict__ q,
                                              float* __restrict__ s, int cols) {
  int row = blockIdx.x;
  int t = threadIdx.x;
  const float* wr = w + (long)row * cols;
  float acc = 0.f;
  for (int c = t; c < cols; c += 256) acc += fabsf(wr[c]);
  __shared__ float red[256];
  red[t] = acc;
  __syncthreads();
  for (int off = 128; off; off >>= 1) {
    if (t < off) red[t] += red[t + off];
    __syncthreads();
  }
  float scale = fmaxf(red[0] / (float)cols, 1e-5f);
  if (t == 0) s[row] = scale;
  bf16* outr = q + (long)row * cols;
  for (int c = t; c < cols; c += 256) {
    float qv = rintf(wr[c] / scale);  // RNE, matches jnp.round
    qv = fmaxf(-1.f, fminf(1.f, qv));
    outr[c] = (bf16)qv;
  }
}

// combine top-2 experts (gathered f32 y), add residual, LN -> f32 + 3-split
__global__ __launch_bounds__(128) void k_lncomb(
    const float* __restrict__ yg, const int* __restrict__ tokpos,
    const float* __restrict__ v2, const float* __restrict__ xBf,
    const float* __restrict__ g, const float* __restrict__ b,
    float* __restrict__ xof, bf16* __restrict__ x0, bf16* __restrict__ x1,
    bf16* __restrict__ x2) {
  int n = blockIdx.x;
  int t = threadIdx.x;
  __shared__ float red[128];
  long tp0 = tokpos[2 * n], tp1 = tokpos[2 * n + 1];
  float w0 = v2[2 * n], w1 = v2[2 * n + 1];
  const float* y0 = yg + tp0 * DIMD;
  const float* y1 = yg + tp1 * DIMD;
  float u[4];
  float s = 0.f;
#pragma unroll
  for (int i = 0; i < 4; ++i) {
    int d = t + i * 128;
    float v = xBf[(long)n * DIMD + d] + w0 * y0[d] + w1 * y1[d];
    u[i] = v;
    s += v;
  }
  red[t] = s;
  __syncthreads();
  for (int off = 64; off; off >>= 1) {
    if (t < off) red[t] += red[t + off];
    __syncthreads();
  }
  float mu = red[0] / (float)DIMD;
  __syncthreads();
  float var = 0.f;
#pragma unroll
  for (int i = 0; i < 4; ++i) {
    float d = u[i] - mu;
    var += d * d;
  }
  red[t] = var;
  __syncthreads();
  for (int off = 64; off; off >>= 1) {
    if (t < off) red[t] += red[t + off];
    __syncthreads();
  }
  float inv = 1.f / sqrtf(red[0] / (float)DIMD + 1e-5f);
#pragma unroll
  for (int i = 0; i < 4; ++i) {
    int c = t + i * 128;
    float v = (u[i] - mu) * inv * g[c] + b[c];
    long oi = (long)n * DIMD + c;
    xof[oi] = v;
    bf16 b0 = (bf16)v;
    float r = v - (float)b0;
    bf16 b1 = (bf16)r;
    x0[oi] = b0; x1[oi] = b1; x2[oi] = (bf16)(r - (float)b1);
  }
}

extern "C" void kernel_launch(void* const* d_in, const int* in_sizes, int n_in,
                              void* d_out, int out_size, void* d_ws, size_t ws_size,
                              hipStream_t stream) {
  const int* ids = (const int*)d_in[0];
  const float* embed = (const float*)d_in[1];
  const float* qkv_w = (const float*)d_in[2];
  const float* out_w = (const float*)d_in[3];
  const float* router_w = (const float*)d_in[4];
  const float* router_b = (const float*)d_in[5];
  const float* w1 = (const float*)d_in[6];
  const float* b1 = (const float*)d_in[7];
  const float* w2 = (const float*)d_in[8];
  const float* b2 = (const float*)d_in[9];
  const float* ln_g = (const float*)d_in[10];
  const float* ln_b = (const float*)d_in[11];
  const float* head_w = (const float*)d_in[12];
  float* out = (float*)d_out;

  char* base = (char*)d_ws;
  size_t off = 0;
  auto alloc = [&](size_t bytes) -> void* {
    void* p = base + off;
    off += (bytes + 255) & ~(size_t)255;
    return p;
  };
  const size_t ND = (size_t)NTOK * DIMD;
  float* xAf = (float*)alloc(ND * 4);
  float* xBf = (float*)alloc(ND * 4);
  float* qkvb = (float*)alloc(ND * 3 * 4);
  int* top2 = (int*)alloc((size_t)NTOK * 2 * 4);
  float* v2 = (float*)alloc((size_t)NTOK * 2 * 4);
  int* perm = (int*)alloc((size_t)EXPERTS * 2048 * 4);
  int* tokpos = (int*)alloc((size_t)NTOK * 2 * 4);
  int* cntb = (int*)alloc(64);
  bf16* xA0 = (bf16*)alloc(ND * 2);
  bf16* xA1 = (bf16*)alloc(ND * 2);
  bf16* xA2 = (bf16*)alloc(ND * 2);
  bf16* xB0 = (bf16*)alloc((ND + DIMD) * 2);  // +1 zero row (idx 2048)
  bf16* xB1 = (bf16*)alloc((ND + DIMD) * 2);
  bf16* xB2 = (bf16*)alloc((ND + DIMD) * 2);
  bf16* at0 = (bf16*)alloc(ND * 2);
  bf16* at1 = (bf16*)alloc(ND * 2);
  bf16* qw0 = (bf16*)alloc((size_t)3 * DIMD * DIMD * 2);
  bf16* qw1 = (bf16*)alloc((size_t)3 * DIMD * DIMD * 2);
  bf16* qw2 = (bf16*)alloc((size_t)3 * DIMD * DIMD * 2);
  bf16* ow0 = (bf16*)alloc((size_t)DIMD * DIMD * 2);
  bf16* ow1 = (bf16*)alloc((size_t)DIMD * DIMD * 2);
  bf16* ow2 = (bf16*)alloc((size_t)DIMD * DIMD * 2);
  bf16* q0b = (bf16*)alloc((size_t)16 * SEQ * HD * 2);
  bf16* q1b = (bf16*)alloc((size_t)16 * SEQ * HD * 2);
  bf16* k0b = (bf16*)alloc((size_t)16 * SEQ * HD * 2);
  bf16* k1b = (bf16*)alloc((size_t)16 * SEQ * HD * 2);
  bf16* vt0b = (bf16*)alloc((size_t)16 * 128 * SEQ * 2);  // 128 rows: pad
  bf16* vt1b = (bf16*)alloc((size_t)16 * 128 * SEQ * 2);
  float* attnf = (float*)alloc((size_t)16 * SEQ * HD * 4);

  // ---- union region (time-multiplexed) ----
  size_t Ustart = off;
  // layout A: attention probabilities (2-split bf16, 32MB each)
  bf16* p0b = (bf16*)(base + Ustart);
  bf16* p1b = (bf16*)(base + Ustart + ((size_t)32 << 20));
  size_t endA = Ustart + ((size_t)64 << 20);
  // layout B: expert scratch (gathered layouts, 2048 rows/expert stride)
  bf16* we1q = (bf16*)alloc((size_t)EXPERTS * FF * DIMD * 2);
  float* s1 = (float*)alloc((size_t)EXPERTS * FF * 4);
  bf16* we2q = (bf16*)alloc((size_t)EXPERTS * DIMD * FF * 2);
  float* s2 = (float*)alloc((size_t)EXPERTS * DIMD * 4);
  bf16* h0g = (bf16*)alloc((size_t)EXPERTS * 2048 * FF * 2);
  bf16* h1g = (bf16*)alloc((size_t)EXPERTS * 2048 * FF * 2);
  float* yg = (float*)alloc((size_t)EXPERTS * 2048 * DIMD * 4);
  size_t endB = off;
  // layout C: head weights
  size_t endC = Ustart + (size_t)HROWS * DIMD * 2;
  bf16* hw0 = (bf16*)(base + Ustart);
  off = endA > endB ? endA : endB;
  if (endC > off) off = endC;
  if (ws_size < off) return;

  k_embed<<<(NTOK * DIMD + 255) / 256, 256, 0, stream>>>(ids, embed, xAf, xA0,
                                                         xA1, xA2);

  for (int l = 0; l < NLAYER; ++l) {
    const float* qw = qkv_w + (long)l * 3 * DIMD * DIMD;
    const float* ow = out_w + (long)l * DIMD * DIMD;
    long nq8 = (long)3 * DIMD * DIMD / 8;
    long no8 = (long)DIMD * DIMD / 8;
    k_split3<<<(int)((nq8 + 255) / 256), 256, 0, stream>>>(qw, qw0, qw1, qw2, nq8);
    k_split3<<<(int)((no8 + 255) / 256), 256, 0, stream>>>(ow, ow0, ow1, ow2, no8);
    // qkv = x @ qkv_w^T  (~f32: 3x3 split, 6 combos, fused single pass)
    k_gemm<3, 3, 0x5F, false><<<dim3(NTOK / 128, (3 * DIMD) / 128, 1), 256, 0,
                                stream>>>(
        xA0, xA1, xA2, qw0, qw1, qw2, qkvb, nullptr, nullptr, nullptr,
        NTOK, 3 * DIMD, DIMD, 0, 0, 0, 0, nullptr, 0, nullptr, 0, nullptr, 0,
        nullptr, nullptr);
    // MFMA attention
    k_qkprep<<<(16 * SEQ * HD + 255) / 256, 256, 0, stream>>>(qkvb, q0b, q1b,
                                                              k0b, k1b);
    k_vtprep<<<(16 * HD * SEQ + 255) / 256, 256, 0, stream>>>(qkvb, vt0b, vt1b);
    // scores = (Q*0.125) @ K^T -> 2-split bf16 [bh][q][k]
    k_gemm<2, 2, 0x0B, false><<<dim3(SEQ / 128, SEQ / 128, 16), 256, 0,
                                stream>>>(
        q0b, q1b, nullptr, k0b, k1b, nullptr, nullptr, p0b, p1b, nullptr,
        SEQ, SEQ, HD, (long)SEQ * HD, (long)SEQ * HD, 0, (long)SEQ * SEQ,
        nullptr, 0, nullptr, 0, nullptr, 0, nullptr, nullptr);
    k_softmax<<<16 * SEQ, 256, 0, stream>>>(p0b, p1b);
    // O = P @ V   (B = V^T rows, padded to 128)
    k_gemm<2, 2, 0x0B, false><<<dim3(SEQ / 128, 1, 16), 256, 0, stream>>>(
        p0b, p1b, nullptr, vt0b, vt1b, nullptr, attnf, nullptr, nullptr,
        nullptr, SEQ, HD, SEQ, (long)SEQ * SEQ, (long)128 * SEQ,
        (long)SEQ * HD, 0, nullptr, 0, nullptr, 0, nullptr, 0,
        nullptr, nullptr);
    k_atrepack<<<(16 * SEQ * HD + 255) / 256, 256, 0, stream>>>(attnf, at0, at1);
    // xB = attn_o @ out_w^T + xA  (A2 x B3, 5 combos fused)
    k_gemm<2, 3, 0x1F, false><<<dim3(NTOK / 128, DIMD / 128, 1), 256, 0,
                                stream>>>(
        at0, at1, nullptr, ow0, ow1, ow2, xBf, xB0, xB1, xB2,
        NTOK, DIMD, DIMD, 0, 0, 0, 0, nullptr, 0, nullptr, 0, xAf, 0,
        nullptr, nullptr);
    k_router<<<NTOK, 64, 0, stream>>>(xBf, router_w + (long)l * EXPERTS * DIMD,
                                      router_b + l * EXPERTS, top2, v2);
    k_expcnt<<<EXPERTS, 256, 0, stream>>>(top2, perm, tokpos, cntb,
                                          xB0 + ND, xB1 + ND, xB2 + ND);
    k_bitw<<<EXPERTS * FF, 256, 0, stream>>>(w1 + (long)l * EXPERTS * FF * DIMD,
                                             we1q, s1, DIMD);
    k_bitw<<<EXPERTS * DIMD, 256, 0, stream>>>(
        w2 + (long)l * EXPERTS * DIMD * FF, we2q, s2, FF);
    // h[e] = gelu((gather(xB) @ q1[e]^T)*s1 + b1)  (A3 x Bexact, sparse)
    k_gemm<3, 1, 0x49, false><<<dim3(NTOK / 128, FF / 128, EXPERTS), 256, 0,
                                stream>>>(
        xB0, xB1, xB2, we1q, nullptr, nullptr, nullptr, h0g, h1g, nullptr,
        NTOK, FF, DIMD, 0, (long)FF * DIMD, 0, (long)2048 * FF,
        s1, FF, b1 + (long)l * EXPERTS * FF, FF, nullptr, 1, cntb, perm);
    // y[e] = (h[e] @ q2[e]^T)*s2 + b2  (A2 x Bexact, sparse, f32 out)
    k_gemm<2, 1, 0x09, false><<<dim3(NTOK / 128, DIMD / 128, EXPERTS), 256, 0,
                                stream>>>(
        h0g, h1g, nullptr, we2q, nullptr, nullptr, yg, nullptr, nullptr,
        nullptr, NTOK, DIMD, FF, (long)2048 * FF, (long)DIMD * FF,
        (long)2048 * DIMD, 0, s2, DIMD, b2 + (long)l * EXPERTS * DIMD, DIMD,
        nullptr, 0, cntb, nullptr);
    k_lncomb<<<NTOK, 128, 0, stream>>>(yg, tokpos, v2, xBf, ln_g + l * DIMD,
                                       ln_b + l * DIMD, xAf, xA0, xA1, xA2);
  }
  // head: logits = x @ head_w^T  (plain bf16, 2-phase prefetch)
  long nh8 = (long)HROWS * DIMD / 8;
  k_headconv<<<(int)((nh8 + 255) / 256), 256, 0, stream>>>(head_w, hw0);
  k_gemm<1, 1, 0x01, true><<<dim3(NTOK / 128, HROWS / 128, 1), 256, 0,
                             stream>>>(
      xA0, nullptr, nullptr, hw0, nullptr, nullptr, out, nullptr, nullptr,
      nullptr, NTOK, VOCABN, DIMD, 0, 0, 0, 0, nullptr, 0, nullptr, 0,
      nullptr, 0, nullptr, nullptr);
}

// Round 7
// 2864.280 us; speedup vs baseline: 1.2549x; 1.2549x over previous
//
#include <hip/hip_runtime.h>
#include <math.h>
#include <stdint.h>

#define NLAYER 6
#define DIMD 512
#define HEADS 8
#define HD 64
#define EXPERTS 8
#define SEQ 1024
#define NTOK 2048
#define FF 1024
#define VOCABN 50257
#define HROWS 50304  // 393*128 zero-padded head rows

typedef __bf16 bf16;
typedef __bf16 bf16x8 __attribute__((ext_vector_type(8)));
typedef __bf16 bf16x4 __attribute__((ext_vector_type(4)));
typedef float f32x4 __attribute__((ext_vector_type(4)));

__device__ __forceinline__ void gl_lds16(const void* g, void* l) {
  __builtin_amdgcn_global_load_lds(
      (const __attribute__((address_space(1))) void*)(uintptr_t)g,
      (__attribute__((address_space(3))) void*)(uintptr_t)l, 16, 0, 0);
}

// LDS element offset for (row, 16B-chunk), BK=32 tiles: XOR swizzle (2-way = free)
#define LDSW(row, kg) (((row) * 32) + ((((kg) ^ (((row) >> 1) & 3))) << 3))

// ============ multi-pass split-bf16 MFMA GEMM: C = A @ Bt^T ============
// modes: 0:1p  1:6p(~f32 3x3)  2:3p(A3,Bexact)  3:2p(A2,Bexact)
//        4:5p(A2xB3)  5:3p(A2xB2)
// mLimit: per-z row count (blocks with m0>=mLimit[z] exit)
// aperm:  per-z A-row indirection [z*2048+row] (pad rows -> 2048)
// atnout: bf16 outputs written at attention token layout (z=bh, ld=DIMD)
__global__ __launch_bounds__(256) void k_mfma_gemm(
    const bf16* __restrict__ A0, const bf16* __restrict__ A1,
    const bf16* __restrict__ A2, const bf16* __restrict__ B0,
    const bf16* __restrict__ B1, const bf16* __restrict__ B2,
    float* __restrict__ Cf, bf16* __restrict__ Cb0, bf16* __restrict__ Cb1,
    bf16* __restrict__ Cb2, int M, int N, int K,
    long sA, long sB, long sCf, long sCb,
    const float* __restrict__ colScale, int csStride,
    const float* __restrict__ bias, int biasStride,
    const float* __restrict__ residual, int act, int mode,
    const int* __restrict__ mLimit, const int* __restrict__ aperm,
    int atnout) {
  __shared__ __align__(16) bf16 As[128 * 32];
  __shared__ __align__(16) bf16 Bs[128 * 32];
  int tid = threadIdx.x;
  int z = blockIdx.z;
  // bijective XCD-aware swizzle (m204)
  int nwg = gridDim.x * gridDim.y;
  int flat = blockIdx.y * gridDim.x + blockIdx.x;
  int qq = nwg >> 3, rr = nwg & 7;
  int xcd = flat & 7, ii = flat >> 3;
  int swz = (xcd < rr ? xcd * (qq + 1) : rr * (qq + 1) + (xcd - rr) * qq) + ii;
  int m0 = (swz % gridDim.x) * 128, n0 = (swz / gridDim.x) * 128;
  if (mLimit && m0 >= mLimit[z]) return;
  int w = tid >> 6, lane = tid & 63;
  int wm = (w >> 1) * 64, wn = (w & 1) * 64;
  int r15 = lane & 15, kg = lane >> 4;

  const bf16* PA[3] = {A0, A1, A2};
  const bf16* PB[3] = {B0, B1, B2};
  int pa[6] = {0, 0, 0, 0, 0, 0};
  int pb[6] = {0, 0, 0, 0, 0, 0};
  int np = 1;
  if (mode == 1) {
    np = 6;
    pa[1] = 0; pb[1] = 1; pa[2] = 1; pb[2] = 0; pa[3] = 1; pb[3] = 1;
    pa[4] = 0; pb[4] = 2; pa[5] = 2; pb[5] = 0;
  } else if (mode == 2) {
    np = 3; pa[1] = 1; pa[2] = 2;
  } else if (mode == 3) {
    np = 2; pa[1] = 1;
  } else if (mode == 4) {
    np = 5;
    pa[1] = 0; pb[1] = 1; pa[2] = 1; pb[2] = 0; pa[3] = 0; pb[3] = 2;
    pa[4] = 1; pb[4] = 1;
  } else if (mode == 5) {
    np = 3;
    pa[1] = 0; pb[1] = 1; pa[2] = 1; pb[2] = 0;
  }

  f32x4 acc[4][4] = {};
  int srow = tid >> 2;
  // global source chunk pre-swizzled so linear LDS dest == swizzled layout
  int scol = (((tid & 3) ^ ((tid >> 3) & 3))) << 3;
  long arow0, arow1;
  if (aperm) {
    arow0 = aperm[z * 2048 + m0 + srow];
    arow1 = aperm[z * 2048 + m0 + 64 + srow];
  } else {
    arow0 = m0 + srow;
    arow1 = m0 + 64 + srow;
  }
  bf16* la0 = &As[tid * 8];
  bf16* la1 = &As[64 * 32 + tid * 8];
  bf16* lb0 = &Bs[tid * 8];
  bf16* lb1 = &Bs[64 * 32 + tid * 8];

  for (int p = 0; p < np; ++p) {
    const bf16* Az = PA[pa[p]] + (long)z * sA;
    const bf16* Bz = PB[pb[p]] + (long)z * sB;
    const bf16* ga0 = Az + arow0 * K + scol;
    const bf16* ga1 = Az + arow1 * K + scol;
    const bf16* gb0 = Bz + (long)(n0 + srow) * K + scol;
    const bf16* gb1 = Bz + (long)(n0 + 64 + srow) * K + scol;
    for (int k0 = 0; k0 < K; k0 += 32) {
      gl_lds16(ga0, la0);
      gl_lds16(ga1, la1);
      gl_lds16(gb0, lb0);
      gl_lds16(gb1, lb1);
      ga0 += 32; ga1 += 32; gb0 += 32; gb1 += 32;
      __syncthreads();  // drains vmcnt: tiles ready
      bf16x8 af[4], bfr[4];
#pragma unroll
      for (int mi = 0; mi < 4; ++mi) {
        int rowA = wm + mi * 16 + r15;
        af[mi] = *(const bf16x8*)&As[LDSW(rowA, kg)];
      }
#pragma unroll
      for (int ni = 0; ni < 4; ++ni) {
        int rowB = wn + ni * 16 + r15;
        bfr[ni] = *(const bf16x8*)&Bs[LDSW(rowB, kg)];
      }
#pragma unroll
      for (int mi = 0; mi < 4; ++mi)
#pragma unroll
        for (int ni = 0; ni < 4; ++ni)
          acc[mi][ni] = __builtin_amdgcn_mfma_f32_16x16x32_bf16(
              af[mi], bfr[ni], acc[mi][ni], 0, 0, 0);
      __syncthreads();  // reads done before next overwrite
    }
  }

  // C/D layout: col=lane&15, row=(lane>>4)*4+reg  [m89]
#pragma unroll
  for (int mi = 0; mi < 4; ++mi) {
    int rbase = m0 + wm + mi * 16 + kg * 4;
#pragma unroll
    for (int ni = 0; ni < 4; ++ni) {
      int col = n0 + wn + ni * 16 + r15;
      if (col >= N) continue;
      float scl = colScale ? colScale[z * csStride + col] : 1.f;
      float bv = bias ? bias[z * biasStride + col] : 0.f;
#pragma unroll
      for (int reg = 0; reg < 4; ++reg) {
        int row = rbase + reg;
        float v = acc[mi][ni][reg] * scl + bv;
        if (act) v = 0.5f * v * (1.f + erff(v * 0.70710678118654752f));
        if (residual) v += residual[(long)row * N + col];
        if (Cf) Cf[z * sCf + (long)row * N + col] = v;
        if (Cb0) {
          long cib = atnout
                         ? ((long)(z >> 3) * ((long)SEQ * DIMD) +
                            (long)(z & 7) * HD + (long)row * DIMD + col)
                         : (z * sCb + (long)row * N + col);
          bf16 h0 = (bf16)v;
          Cb0[cib] = h0;
          if (Cb1) {
            float r = v - (float)h0;
            bf16 h1 = (bf16)r;
            Cb1[cib] = h1;
            if (Cb2) Cb2[cib] = (bf16)(r - (float)h1);
          }
        }
      }
    }
  }
}

// ====== dedicated head GEMM: BK=64, chunk-XOR swizzle, plain bf16 ======
__global__ __launch_bounds__(256) void k_hgemm(const bf16* __restrict__ A,
                                               const bf16* __restrict__ Bt,
                                               float* __restrict__ C,
                                               int M, int N, int K) {
  __shared__ __align__(16) bf16 As[128 * 64];
  __shared__ __align__(16) bf16 Bs[128 * 64];
  int tid = threadIdx.x;
  int nwg = gridDim.x * gridDim.y;
  int flat = blockIdx.y * gridDim.x + blockIdx.x;
  int qq = nwg >> 3, rr = nwg & 7;
  int xcd = flat & 7, ii = flat >> 3;
  int swz = (xcd < rr ? xcd * (qq + 1) : rr * (qq + 1) + (xcd - rr) * qq) + ii;
  int m0 = (swz % gridDim.x) * 128, n0 = (swz / gridDim.x) * 128;
  int w = tid >> 6, lane = tid & 63;
  int wm = (w >> 1) * 64, wn = (w & 1) * 64;
  int r15 = lane & 15, kg = lane >> 4;
  int srow = tid >> 3;  // 0..31
  // phys chunk (t&7) holds global chunk (t&7)^(row&7); row&7 == (t>>3)&7
  int scol = (((tid & 7) ^ ((tid >> 3) & 7))) << 3;
  const bf16* ga = A + (long)(m0 + srow) * K + scol;
  const bf16* gb = Bt + (long)(n0 + srow) * K + scol;
  f32x4 acc[4][4] = {};
  for (int k0 = 0; k0 < K; k0 += 64) {
#pragma unroll
    for (int i = 0; i < 4; ++i) {
      gl_lds16(ga + (long)i * 32 * K + k0, &As[i * 2048 + tid * 8]);
      gl_lds16(gb + (long)i * 32 * K + k0, &Bs[i * 2048 + tid * 8]);
    }
    __syncthreads();  // tiles ready
#pragma unroll
    for (int kk = 0; kk < 2; ++kk) {
      bf16x8 af[4], bf_[4];
#pragma unroll
      for (int mi = 0; mi < 4; ++mi) {
        int rowA = wm + mi * 16 + r15;
        af[mi] = *(const bf16x8*)
            &As[rowA * 64 + ((((kk * 4 + kg) ^ (rowA & 7))) << 3)];
      }
#pragma unroll
      for (int ni = 0; ni < 4; ++ni) {
        int rowB = wn + ni * 16 + r15;
        bf_[ni] = *(const bf16x8*)
            &Bs[rowB * 64 + ((((kk * 4 + kg) ^ (rowB & 7))) << 3)];
      }
#pragma unroll
      for (int mi = 0; mi < 4; ++mi)
#pragma unroll
        for (int ni = 0; ni < 4; ++ni)
          acc[mi][ni] = __builtin_amdgcn_mfma_f32_16x16x32_bf16(
              af[mi], bf_[ni], acc[mi][ni], 0, 0, 0);
    }
    __syncthreads();  // reads done before overwrite
  }
#pragma unroll
  for (int mi = 0; mi < 4; ++mi) {
    int rbase = m0 + wm + mi * 16 + kg * 4;
#pragma unroll
    for (int ni = 0; ni < 4; ++ni) {
      int col = n0 + wn + ni * 16 + r15;
      if (col >= N) continue;
#pragma unroll
      for (int reg = 0; reg < 4; ++reg)
        C[(long)(rbase + reg) * N + col] = acc[mi][ni][reg];
    }
  }
}

// ---------------- helpers ----------------
__global__ __launch_bounds__(256) void k_embed(const int* __restrict__ ids,
                                               const float* __restrict__ E,
                                               float* __restrict__ xf,
                                               bf16* __restrict__ x0,
                                               bf16* __restrict__ x1,
                                               bf16* __restrict__ x2) {
  int i = blockIdx.x * 256 + threadIdx.x;
  if (i >= NTOK * DIMD) return;
  int n = i >> 9, d = i & 511;
  float v = E[(long)ids[n] * DIMD + d];
  xf[i] = v;
  bf16 b0 = (bf16)v;
  float r = v - (float)b0;
  bf16 b1 = (bf16)r;
  x0[i] = b0; x1[i] = b1; x2[i] = (bf16)(r - (float)b1);
}

__global__ __launch_bounds__(256) void k_split3(const float* __restrict__ s,
                                                bf16* __restrict__ d0,
                                                bf16* __restrict__ d1,
                                                bf16* __restrict__ d2, long n8) {
  long i = (long)blockIdx.x * 256 + threadIdx.x;
  if (i >= n8) return;
  const float4* s4 = (const float4*)s;
  float4 a = s4[2 * i], b = s4[2 * i + 1];
  float vv[8] = {a.x, a.y, a.z, a.w, b.x, b.y, b.z, b.w};
  bf16x8 o0, o1, o2;
#pragma unroll
  for (int j = 0; j < 8; ++j) {
    float v = vv[j];
    bf16 h0 = (bf16)v;
    float r = v - (float)h0;
    bf16 h1 = (bf16)r;
    o0[j] = h0; o1[j] = h1; o2[j] = (bf16)(r - (float)h1);
  }
  ((bf16x8*)d0)[i] = o0;
  ((bf16x8*)d1)[i] = o1;
  ((bf16x8*)d2)[i] = o2;
}

__global__ __launch_bounds__(256) void k_headconv(const float* __restrict__ s,
                                                  bf16* __restrict__ d) {
  long i = (long)blockIdx.x * 256 + threadIdx.x;
  long n8 = (long)HROWS * DIMD / 8;
  if (i >= n8) return;
  long row = i / (DIMD / 8);
  bf16x8 o;
  if (row < VOCABN) {
    const float4* s4 = (const float4*)s;
    float4 a = s4[2 * i], b = s4[2 * i + 1];
    o[0] = (bf16)a.x; o[1] = (bf16)a.y; o[2] = (bf16)a.z; o[3] = (bf16)a.w;
    o[4] = (bf16)b.x; o[5] = (bf16)b.y; o[6] = (bf16)b.z; o[7] = (bf16)b.w;
  } else {
    o = (bf16x8)(bf16)0.f;
  }
  ((bf16x8*)d)[i] = o;
}

// Q,K 2-splits from f32 qkv (token layout); Q pre-scaled by 0.125 (exact)
__global__ __launch_bounds__(256) void k_qkprep(const float* __restrict__ qkv,
                                                bf16* __restrict__ q0,
                                                bf16* __restrict__ q1,
                                                bf16* __restrict__ k0,
                                                bf16* __restrict__ k1) {
  int i = blockIdx.x * 256 + threadIdx.x;  // [bh][q][d] flat
  if (i >= 16 * SEQ * HD) return;
  int d = i & 63, q = (i >> 6) & (SEQ - 1), bh = i >> 16;
  int b = bh >> 3, h = bh & 7;
  long src = ((long)(b * SEQ + q)) * (3 * DIMD) + h * HD + d;
  float qv = qkv[src] * 0.125f;
  float kv = qkv[src + DIMD];
  bf16 a = (bf16)qv; q0[i] = a; q1[i] = (bf16)(qv - (float)a);
  bf16 c = (bf16)kv; k0[i] = c; k1[i] = (bf16)(kv - (float)c);
}

// V^T 2-splits: vt[bh][d][k], rows padded to 128 per bh (pad never written)
__global__ __launch_bounds__(256) void k_vtprep(const float* __restrict__ qkv,
                                                bf16* __restrict__ vt0,
                                                bf16* __restrict__ vt1) {
  int i = blockIdx.x * 256 + threadIdx.x;  // [bh][d][k] flat
  if (i >= 16 * HD * SEQ) return;
  int k = i & (SEQ - 1), d = (i >> 10) & 63, bh = i >> 16;
  int b = bh >> 3, h = bh & 7;
  float v = qkv[((long)(b * SEQ + k)) * (3 * DIMD) + 2 * DIMD + h * HD + d];
  long dst = (long)bh * (128 * SEQ) + (long)d * SEQ + k;
  bf16 a = (bf16)v; vt0[dst] = a; vt1[dst] = (bf16)(v - (float)a);
}

// row softmax over P[16*SEQ][SEQ] f32 -> 2-split bf16 (vectorized, G13)
__global__ __launch_bounds__(256) void k_softmax(const float* __restrict__ P,
                                                 bf16* __restrict__ p0,
                                                 bf16* __restrict__ p1) {
  int row = blockIdx.x;
  int t = threadIdx.x;
  long base = (long)row * SEQ;
  float4 v = ((const float4*)(P + base))[t];  // 256 thr x 4 = 1024
  __shared__ float red[256];
  float m = fmaxf(fmaxf(v.x, v.y), fmaxf(v.z, v.w));
  red[t] = m;
  __syncthreads();
  for (int off = 128; off; off >>= 1) {
    if (t < off) red[t] = fmaxf(red[t], red[t + off]);
    __syncthreads();
  }
  m = red[0];
  __syncthreads();
  v.x = __expf(v.x - m); v.y = __expf(v.y - m);
  v.z = __expf(v.z - m); v.w = __expf(v.w - m);
  red[t] = v.x + v.y + v.z + v.w;
  __syncthreads();
  for (int off = 128; off; off >>= 1) {
    if (t < off) red[t] += red[t + off];
    __syncthreads();
  }
  float inv = 1.f / red[0];
  float pv[4] = {v.x * inv, v.y * inv, v.z * inv, v.w * inv};
  bf16x4 o0, o1;
#pragma unroll
  for (int j = 0; j < 4; ++j) {
    bf16 h0 = (bf16)pv[j];
    o0[j] = h0;
    o1[j] = (bf16)(pv[j] - (float)h0);
  }
  ((bf16x4*)(p0 + base))[t] = o0;
  ((bf16x4*)(p1 + base))[t] = o1;
}

// router: top-2 expert ids + normalized weights per token
__global__ __launch_bounds__(64) void k_router(const float* __restrict__ x,
                                               const float* __restrict__ rw,
                                               const float* __restrict__ rb,
                                               int* __restrict__ top2,
                                               float* __restrict__ v2) {
  int n = blockIdx.x;
  int t = threadIdx.x;
  int e = t >> 3, part = t & 7;
  __shared__ float red[64];
  const float* xr = x + (long)n * DIMD;
  const float* wr = rw + (long)e * DIMD;
  float d = 0.f;
  int c0 = part * 64;
#pragma unroll
  for (int c = 0; c < 64; c += 4) {
    float4 xv = *(const float4*)(xr + c0 + c);
    float4 wv = *(const float4*)(wr + c0 + c);
    d += xv.x * wv.x + xv.y * wv.y + xv.z * wv.z + xv.w * wv.w;
  }
  red[t] = d;
  __syncthreads();
  if (t < 8) {
    float logit = rb[t];
    for (int pp = 0; pp < 8; ++pp) logit += red[t * 8 + pp];
    red[t] = logit;
  }
  __syncthreads();
  if (t == 0) {
    float p2[8];
    float m = -1e30f;
    for (int i = 0; i < 8; ++i) m = fmaxf(m, red[i]);
    float s = 0.f;
    for (int i = 0; i < 8; ++i) { p2[i] = expf(red[i] - m); s += p2[i]; }
    for (int i = 0; i < 8; ++i) p2[i] /= s;
    int i1 = 0;
    for (int i = 1; i < 8; ++i) if (p2[i] > p2[i1]) i1 = i;
    int i2 = (i1 == 0) ? 1 : 0;
    for (int i = 0; i < 8; ++i) {
      if (i == i1 || i == i2) continue;
      if (p2[i] > p2[i2]) i2 = i;
    }
    float sum = p2[i1] + p2[i2] + 1e-8f;
    top2[2 * n] = i1;
    top2[2 * n + 1] = i2;
    v2[2 * n] = p2[i1] / sum;
    v2[2 * n + 1] = p2[i2] / sum;
  }
}

// per-expert token lists, one-pass 8-elem/thread prefix scan (deterministic)
__global__ __launch_bounds__(256) void k_expcnt(const int* __restrict__ top2,
                                                int* __restrict__ perm,
                                                int* __restrict__ tokpos,
                                                int* __restrict__ cnt,
                                                bf16* __restrict__ zx0,
                                                bf16* __restrict__ zx1,
                                                bf16* __restrict__ zx2) {
  int e = blockIdx.x, t = threadIdx.x;
  if (e == 0) {
    for (int c = t; c < DIMD; c += 256) {
      zx0[c] = (bf16)0.f; zx1[c] = (bf16)0.f; zx2[c] = (bf16)0.f;
    }
  }
  __shared__ int sc[256];
  int fl[8];
  int f = 0;
#pragma unroll
  for (int j = 0; j < 8; ++j) {
    int n = t * 8 + j;
    int m = (top2[2 * n] == e || top2[2 * n + 1] == e) ? 1 : 0;
    fl[j] = m;
    f += m;
  }
  sc[t] = f;
  __syncthreads();
  for (int o = 1; o < 256; o <<= 1) {
    int v = (t >= o) ? sc[t - o] : 0;
    __syncthreads();
    sc[t] += v;
    __syncthreads();
  }
  int pos = sc[t] - f;  // exclusive prefix
#pragma unroll
  for (int j = 0; j < 8; ++j) {
    if (fl[j]) {
      int n = t * 8 + j;
      perm[e * 2048 + pos] = n;
      int jj = (top2[2 * n] == e) ? 0 : 1;
      tokpos[2 * n + jj] = e * 2048 + pos;
      ++pos;
    }
  }
  int total = sc[255];
  int cpad = (total + 127) & ~127;
  for (int i = total + t; i < cpad; i += 256) perm[e * 2048 + i] = 2048;
  if (t == 0) cnt[e] = total;
}

// BitNet: q in {-1,0,1} (exact bf16) + per-row f32 scale
__global__ __launch_bounds__(256) void k_bitw(const float* __restrict__ w,
                                              bf16* __restrict__ q,
                                              float* __restrict__ s, int cols) {
  int row = blockIdx.x;
  int t = threadIdx.x;
  const float* wr = w + (long)row * cols;
  float acc = 0.f;
  for (int c = t; c < cols; c += 256) acc += fabsf(wr[c]);
  __shared__ float red[256];
  red[t] = acc;
  __syncthreads();
  for (int off = 128; off; off >>= 1) {
    if (t < off) red[t] += red[t + off];
    __syncthreads();
  }
  float scale = fmaxf(red[0] / (float)cols, 1e-5f);
  if (t == 0) s[row] = scale;
  bf16* outr = q + (long)row * cols;
  for (int c = t; c < cols; c += 256) {
    float qv = rintf(wr[c] / scale);  // RNE, matches jnp.round
    qv = fmaxf(-1.f, fminf(1.f, qv));
    outr[c] = (bf16)qv;
  }
}

// combine top-2 experts (gathered f32 y), add residual, LN -> f32 + 3-split
__global__ __launch_bounds__(128) void k_lncomb(
    const float* __restrict__ yg, const int* __restrict__ tokpos,
    const float* __restrict__ v2, const float* __restrict__ xBf,
    const float* __restrict__ g, const float* __restrict__ b,
    float* __restrict__ xof, bf16* __restrict__ x0, bf16* __restrict__ x1,
    bf16* __restrict__ x2) {
  int n = blockIdx.x;
  int t = threadIdx.x;
  __shared__ float red[128];
  long tp0 = tokpos[2 * n], tp1 = tokpos[2 * n + 1];
  float w0 = v2[2 * n], w1 = v2[2 * n + 1];
  const float* y0 = yg + tp0 * DIMD;
  const float* y1 = yg + tp1 * DIMD;
  float u[4];
  float s = 0.f;
#pragma unroll
  for (int i = 0; i < 4; ++i) {
    int d = t + i * 128;
    float v = xBf[(long)n * DIMD + d] + w0 * y0[d] + w1 * y1[d];
    u[i] = v;
    s += v;
  }
  red[t] = s;
  __syncthreads();
  for (int off = 64; off; off >>= 1) {
    if (t < off) red[t] += red[t + off];
    __syncthreads();
  }
  float mu = red[0] / (float)DIMD;
  __syncthreads();
  float var = 0.f;
#pragma unroll
  for (int i = 0; i < 4; ++i) {
    float d = u[i] - mu;
    var += d * d;
  }
  red[t] = var;
  __syncthreads();
  for (int off = 64; off; off >>= 1) {
    if (t < off) red[t] += red[t + off];
    __syncthreads();
  }
  float inv = 1.f / sqrtf(red[0] / (float)DIMD + 1e-5f);
#pragma unroll
  for (int i = 0; i < 4; ++i) {
    int c = t + i * 128;
    float v = (u[i] - mu) * inv * g[c] + b[c];
    long oi = (long)n * DIMD + c;
    xof[oi] = v;
    bf16 b0 = (bf16)v;
    float r = v - (float)b0;
    bf16 b1 = (bf16)r;
    x0[oi] = b0; x1[oi] = b1; x2[oi] = (bf16)(r - (float)b1);
  }
}

extern "C" void kernel_launch(void* const* d_in, const int* in_sizes, int n_in,
                              void* d_out, int out_size, void* d_ws, size_t ws_size,
                              hipStream_t stream) {
  const int* ids = (const int*)d_in[0];
  const float* embed = (const float*)d_in[1];
  const float* qkv_w = (const float*)d_in[2];
  const float* out_w = (const float*)d_in[3];
  const float* router_w = (const float*)d_in[4];
  const float* router_b = (const float*)d_in[5];
  const float* w1 = (const float*)d_in[6];
  const float* b1 = (const float*)d_in[7];
  const float* w2 = (const float*)d_in[8];
  const float* b2 = (const float*)d_in[9];
  const float* ln_g = (const float*)d_in[10];
  const float* ln_b = (const float*)d_in[11];
  const float* head_w = (const float*)d_in[12];
  float* out = (float*)d_out;

  char* base = (char*)d_ws;
  size_t off = 0;
  auto alloc = [&](size_t bytes) -> void* {
    void* p = base + off;
    off += (bytes + 255) & ~(size_t)255;
    return p;
  };
  const size_t ND = (size_t)NTOK * DIMD;
  float* xAf = (float*)alloc(ND * 4);
  float* xBf = (float*)alloc(ND * 4);
  float* qkvb = (float*)alloc(ND * 3 * 4);
  int* top2 = (int*)alloc((size_t)NTOK * 2 * 4);
  float* v2 = (float*)alloc((size_t)NTOK * 2 * 4);
  int* perm = (int*)alloc((size_t)EXPERTS * 2048 * 4);
  int* tokpos = (int*)alloc((size_t)NTOK * 2 * 4);
  int* cntb = (int*)alloc(64);
  bf16* xA0 = (bf16*)alloc(ND * 2);
  bf16* xA1 = (bf16*)alloc(ND * 2);
  bf16* xA2 = (bf16*)alloc(ND * 2);
  bf16* xB0 = (bf16*)alloc((ND + DIMD) * 2);  // +1 zero row (idx 2048)
  bf16* xB1 = (bf16*)alloc((ND + DIMD) * 2);
  bf16* xB2 = (bf16*)alloc((ND + DIMD) * 2);
  bf16* at0 = (bf16*)alloc(ND * 2);
  bf16* at1 = (bf16*)alloc(ND * 2);
  bf16* qw0 = (bf16*)alloc((size_t)3 * DIMD * DIMD * 2);
  bf16* qw1 = (bf16*)alloc((size_t)3 * DIMD * DIMD * 2);
  bf16* qw2 = (bf16*)alloc((size_t)3 * DIMD * DIMD * 2);
  bf16* ow0 = (bf16*)alloc((size_t)DIMD * DIMD * 2);
  bf16* ow1 = (bf16*)alloc((size_t)DIMD * DIMD * 2);
  bf16* ow2 = (bf16*)alloc((size_t)DIMD * DIMD * 2);
  bf16* q0b = (bf16*)alloc((size_t)16 * SEQ * HD * 2);
  bf16* q1b = (bf16*)alloc((size_t)16 * SEQ * HD * 2);
  bf16* k0b = (bf16*)alloc((size_t)16 * SEQ * HD * 2);
  bf16* k1b = (bf16*)alloc((size_t)16 * SEQ * HD * 2);
  bf16* vt0b = (bf16*)alloc((size_t)16 * 128 * SEQ * 2);  // 128 rows: pad
  bf16* vt1b = (bf16*)alloc((size_t)16 * 128 * SEQ * 2);

  // ---- union region (time-multiplexed) ----
  size_t Ustart = off;
  // layout A: attention scores (f32) + 2-split probabilities
  float* Pbuf = (float*)(base + Ustart);
  bf16* p0b = (bf16*)(base + Ustart + ((size_t)64 << 20));
  bf16* p1b = (bf16*)(base + Ustart + ((size_t)96 << 20));
  size_t endA = Ustart + ((size_t)128 << 20);
  // layout B: expert scratch (gathered layouts, 2048 rows/expert stride)
  bf16* we1q = (bf16*)alloc((size_t)EXPERTS * FF * DIMD * 2);
  float* s1 = (float*)alloc((size_t)EXPERTS * FF * 4);
  bf16* we2q = (bf16*)alloc((size_t)EXPERTS * DIMD * FF * 2);
  float* s2 = (float*)alloc((size_t)EXPERTS * DIMD * 4);
  bf16* h0g = (bf16*)alloc((size_t)EXPERTS * 2048 * FF * 2);
  bf16* h1g = (bf16*)alloc((size_t)EXPERTS * 2048 * FF * 2);
  float* yg = (float*)alloc((size_t)EXPERTS * 2048 * DIMD * 4);
  size_t endB = off;
  // layout C: head weights
  size_t endC = Ustart + (size_t)HROWS * DIMD * 2;
  bf16* hw0 = (bf16*)(base + Ustart);
  off = endA > endB ? endA : endB;
  if (endC > off) off = endC;
  if (ws_size < off) return;

  k_embed<<<(NTOK * DIMD + 255) / 256, 256, 0, stream>>>(ids, embed, xAf, xA0,
                                                         xA1, xA2);

  for (int l = 0; l < NLAYER; ++l) {
    const float* qw = qkv_w + (long)l * 3 * DIMD * DIMD;
    const float* ow = out_w + (long)l * DIMD * DIMD;
    long nq8 = (long)3 * DIMD * DIMD / 8;
    long no8 = (long)DIMD * DIMD / 8;
    k_split3<<<(int)((nq8 + 255) / 256), 256, 0, stream>>>(qw, qw0, qw1, qw2, nq8);
    k_split3<<<(int)((no8 + 255) / 256), 256, 0, stream>>>(ow, ow0, ow1, ow2, no8);
    // qkv = x @ qkv_w^T  (mode 1: ~f32, f32 out)
    k_mfma_gemm<<<dim3(NTOK / 128, (3 * DIMD) / 128, 1), 256, 0, stream>>>(
        xA0, xA1, xA2, qw0, qw1, qw2, qkvb, nullptr, nullptr, nullptr,
        NTOK, 3 * DIMD, DIMD, 0, 0, 0, 0, nullptr, 0, nullptr, 0, nullptr, 0,
        1, nullptr, nullptr, 0);
    // MFMA attention
    k_qkprep<<<(16 * SEQ * HD + 255) / 256, 256, 0, stream>>>(qkvb, q0b, q1b,
                                                              k0b, k1b);
    k_vtprep<<<(16 * HD * SEQ + 255) / 256, 256, 0, stream>>>(qkvb, vt0b, vt1b);
    // P = (Q*0.125) @ K^T   [bh][q][k] f32
    k_mfma_gemm<<<dim3(SEQ / 128, SEQ / 128, 16), 256, 0, stream>>>(
        q0b, q1b, nullptr, k0b, k1b, nullptr, Pbuf, nullptr, nullptr, nullptr,
        SEQ, SEQ, HD, (long)SEQ * HD, (long)SEQ * HD, (long)SEQ * SEQ, 0,
        nullptr, 0, nullptr, 0, nullptr, 0, 5, nullptr, nullptr, 0);
    k_softmax<<<16 * SEQ, 256, 0, stream>>>(Pbuf, p0b, p1b);
    // O = P @ V  -> token-layout 2-split directly (atnout epilogue)
    k_mfma_gemm<<<dim3(SEQ / 128, 1, 16), 256, 0, stream>>>(
        p0b, p1b, nullptr, vt0b, vt1b, nullptr, nullptr, at0, at1, nullptr,
        SEQ, HD, SEQ, (long)SEQ * SEQ, (long)128 * SEQ, 0, 0,
        nullptr, 0, nullptr, 0, nullptr, 0, 5, nullptr, nullptr, 1);
    // xB = attn_o @ out_w^T + xA  (mode 4; f32 + 3-split out)
    k_mfma_gemm<<<dim3(NTOK / 128, DIMD / 128, 1), 256, 0, stream>>>(
        at0, at1, nullptr, ow0, ow1, ow2, xBf, xB0, xB1, xB2,
        NTOK, DIMD, DIMD, 0, 0, 0, 0, nullptr, 0, nullptr, 0, xAf, 0, 4,
        nullptr, nullptr, 0);
    k_router<<<NTOK, 64, 0, stream>>>(xBf, router_w + (long)l * EXPERTS * DIMD,
                                      router_b + l * EXPERTS, top2, v2);
    k_expcnt<<<EXPERTS, 256, 0, stream>>>(top2, perm, tokpos, cntb,
                                          xB0 + ND, xB1 + ND, xB2 + ND);
    k_bitw<<<EXPERTS * FF, 256, 0, stream>>>(w1 + (long)l * EXPERTS * FF * DIMD,
                                             we1q, s1, DIMD);
    k_bitw<<<EXPERTS * DIMD, 256, 0, stream>>>(
        w2 + (long)l * EXPERTS * DIMD * FF, we2q, s2, FF);
    // h[e] = gelu((gather(xB) @ q1[e]^T)*s1 + b1)  (mode 2, A-perm, sparse)
    k_mfma_gemm<<<dim3(NTOK / 128, FF / 128, EXPERTS), 256, 0, stream>>>(
        xB0, xB1, xB2, we1q, nullptr, nullptr, nullptr, h0g, h1g, nullptr,
        NTOK, FF, DIMD, 0, (long)FF * DIMD, 0, (long)2048 * FF,
        s1, FF, b1 + (long)l * EXPERTS * FF, FF, nullptr, 1, 2, cntb, perm, 0);
    // y[e] = (h[e] @ q2[e]^T)*s2 + b2  (mode 3, sparse, f32 out)
    k_mfma_gemm<<<dim3(NTOK / 128, DIMD / 128, EXPERTS), 256, 0, stream>>>(
        h0g, h1g, nullptr, we2q, nullptr, nullptr, yg, nullptr, nullptr,
        nullptr, NTOK, DIMD, FF, (long)2048 * FF, (long)DIMD * FF,
        (long)2048 * DIMD, 0, s2, DIMD, b2 + (long)l * EXPERTS * DIMD, DIMD,
        nullptr, 0, 3, cntb, nullptr, 0);
    k_lncomb<<<NTOK, 128, 0, stream>>>(yg, tokpos, v2, xBf, ln_g + l * DIMD,
                                       ln_b + l * DIMD, xAf, xA0, xA1, xA2);
  }
  // head: logits = x @ head_w^T  (dedicated BK=64 kernel)
  long nh8 = (long)HROWS * DIMD / 8;
  k_headconv<<<(int)((nh8 + 255) / 256), 256, 0, stream>>>(head_w, hw0);
  k_hgemm<<<dim3(NTOK / 128, HROWS / 128, 1), 256, 0, stream>>>(
      xA0, hw0, out, NTOK, VOCABN, DIMD);
}

// Round 8
// 2797.568 us; speedup vs baseline: 1.2849x; 1.0238x over previous
//
#include <hip/hip_runtime.h>
#include <math.h>
#include <stdint.h>

#define NLAYER 6
#define DIMD 512
#define HEADS 8
#define HD 64
#define EXPERTS 8
#define SEQ 1024
#define NTOK 2048
#define FF 1024
#define VOCABN 50257
#define HROWS 50304  // 393*128 zero-padded head rows

typedef __bf16 bf16;
typedef __bf16 bf16x8 __attribute__((ext_vector_type(8)));
typedef __bf16 bf16x4 __attribute__((ext_vector_type(4)));
typedef float f32x4 __attribute__((ext_vector_type(4)));

__device__ __forceinline__ void gl_lds16(const void* g, void* l) {
  __builtin_amdgcn_global_load_lds(
      (const __attribute__((address_space(1))) void*)(uintptr_t)g,
      (__attribute__((address_space(3))) void*)(uintptr_t)l, 16, 0, 0);
}

// LDS element offset for (row, 16B-chunk), BK=32 tiles: XOR swizzle (2-way = free)
#define LDSW(row, kg) (((row) * 32) + ((((kg) ^ (((row) >> 1) & 3))) << 3))

// ============ multi-pass split-bf16 MFMA GEMM: C = A @ Bt^T ============
// modes: 0:1p  3:2p(A2,Bexact)  5:3p(A2xB2)   (1/2/4 retained but unused)
// mLimit: per-z row count (blocks with m0>=mLimit[z] exit)
// aperm:  per-z A-row indirection [z*2048+row] (pad rows -> 2048)
// outmode: 0 normal; 1 bf16 out in attention token layout (z=bh, ld=DIMD);
//          2 qkv-split out: q->(Cb0,Cb1) k->(Cb2,E0) vt->(E1,E2)
__global__ __launch_bounds__(256) void k_mfma_gemm(
    const bf16* __restrict__ A0, const bf16* __restrict__ A1,
    const bf16* __restrict__ A2, const bf16* __restrict__ B0,
    const bf16* __restrict__ B1, const bf16* __restrict__ B2,
    float* __restrict__ Cf, bf16* __restrict__ Cb0, bf16* __restrict__ Cb1,
    bf16* __restrict__ Cb2, bf16* __restrict__ E0, bf16* __restrict__ E1,
    bf16* __restrict__ E2, int M, int N, int K,
    long sA, long sB, long sCf, long sCb,
    const float* __restrict__ colScale, int csStride,
    const float* __restrict__ bias, int biasStride,
    const float* __restrict__ residual, int act, int mode,
    const int* __restrict__ mLimit, const int* __restrict__ aperm,
    int outmode) {
  __shared__ __align__(16) bf16 As[128 * 32];
  __shared__ __align__(16) bf16 Bs[128 * 32];
  int tid = threadIdx.x;
  int z = blockIdx.z;
  // bijective XCD-aware swizzle (m204)
  int nwg = gridDim.x * gridDim.y;
  int flat = blockIdx.y * gridDim.x + blockIdx.x;
  int qq = nwg >> 3, rr = nwg & 7;
  int xcd = flat & 7, ii = flat >> 3;
  int swz = (xcd < rr ? xcd * (qq + 1) : rr * (qq + 1) + (xcd - rr) * qq) + ii;
  int m0 = (swz % gridDim.x) * 128, n0 = (swz / gridDim.x) * 128;
  if (mLimit && m0 >= mLimit[z]) return;
  int w = tid >> 6, lane = tid & 63;
  int wm = (w >> 1) * 64, wn = (w & 1) * 64;
  int r15 = lane & 15, kg = lane >> 4;

  const bf16* PA[3] = {A0, A1, A2};
  const bf16* PB[3] = {B0, B1, B2};
  int pa[6] = {0, 0, 0, 0, 0, 0};
  int pb[6] = {0, 0, 0, 0, 0, 0};
  int np = 1;
  if (mode == 1) {
    np = 6;
    pa[1] = 0; pb[1] = 1; pa[2] = 1; pb[2] = 0; pa[3] = 1; pb[3] = 1;
    pa[4] = 0; pb[4] = 2; pa[5] = 2; pb[5] = 0;
  } else if (mode == 2) {
    np = 3; pa[1] = 1; pa[2] = 2;
  } else if (mode == 3) {
    np = 2; pa[1] = 1;
  } else if (mode == 4) {
    np = 5;
    pa[1] = 0; pb[1] = 1; pa[2] = 1; pb[2] = 0; pa[3] = 0; pb[3] = 2;
    pa[4] = 1; pb[4] = 1;
  } else if (mode == 5) {
    np = 3;
    pa[1] = 0; pb[1] = 1; pa[2] = 1; pb[2] = 0;
  }

  f32x4 acc[4][4] = {};
  int srow = tid >> 2;
  // global source chunk pre-swizzled so linear LDS dest == swizzled layout
  int scol = (((tid & 3) ^ ((tid >> 3) & 3))) << 3;
  long arow0, arow1;
  if (aperm) {
    arow0 = aperm[z * 2048 + m0 + srow];
    arow1 = aperm[z * 2048 + m0 + 64 + srow];
  } else {
    arow0 = m0 + srow;
    arow1 = m0 + 64 + srow;
  }
  bf16* la0 = &As[tid * 8];
  bf16* la1 = &As[64 * 32 + tid * 8];
  bf16* lb0 = &Bs[tid * 8];
  bf16* lb1 = &Bs[64 * 32 + tid * 8];

  for (int p = 0; p < np; ++p) {
    const bf16* Az = PA[pa[p]] + (long)z * sA;
    const bf16* Bz = PB[pb[p]] + (long)z * sB;
    const bf16* ga0 = Az + arow0 * K + scol;
    const bf16* ga1 = Az + arow1 * K + scol;
    const bf16* gb0 = Bz + (long)(n0 + srow) * K + scol;
    const bf16* gb1 = Bz + (long)(n0 + 64 + srow) * K + scol;
    for (int k0 = 0; k0 < K; k0 += 32) {
      gl_lds16(ga0, la0);
      gl_lds16(ga1, la1);
      gl_lds16(gb0, lb0);
      gl_lds16(gb1, lb1);
      ga0 += 32; ga1 += 32; gb0 += 32; gb1 += 32;
      __syncthreads();  // drains vmcnt: tiles ready
      bf16x8 af[4], bfr[4];
#pragma unroll
      for (int mi = 0; mi < 4; ++mi) {
        int rowA = wm + mi * 16 + r15;
        af[mi] = *(const bf16x8*)&As[LDSW(rowA, kg)];
      }
#pragma unroll
      for (int ni = 0; ni < 4; ++ni) {
        int rowB = wn + ni * 16 + r15;
        bfr[ni] = *(const bf16x8*)&Bs[LDSW(rowB, kg)];
      }
#pragma unroll
      for (int mi = 0; mi < 4; ++mi)
#pragma unroll
        for (int ni = 0; ni < 4; ++ni)
          acc[mi][ni] = __builtin_amdgcn_mfma_f32_16x16x32_bf16(
              af[mi], bfr[ni], acc[mi][ni], 0, 0, 0);
      __syncthreads();  // reads done before next overwrite
    }
  }

  // C/D layout: col=lane&15, row=(lane>>4)*4+reg  [m89]
#pragma unroll
  for (int mi = 0; mi < 4; ++mi) {
    int rbase = m0 + wm + mi * 16 + kg * 4;
#pragma unroll
    for (int ni = 0; ni < 4; ++ni) {
      int col = n0 + wn + ni * 16 + r15;
      if (col >= N) continue;
      float scl = colScale ? colScale[z * csStride + col] : 1.f;
      float bv = bias ? bias[z * biasStride + col] : 0.f;
#pragma unroll
      for (int reg = 0; reg < 4; ++reg) {
        int row = rbase + reg;
        float v = acc[mi][ni][reg] * scl + bv;
        if (act) v = 0.5f * v * (1.f + erff(v * 0.70710678118654752f));
        if (residual) v += residual[(long)row * N + col];
        if (outmode == 2) {
          // qkv fused epilogue: region is block-uniform (tile within q/k/v)
          int b = row >> 10, qt = row & 1023;
          if (n0 < 512) {  // Q, pre-scaled by 0.125 (exact)
            float qv = v * 0.125f;
            int h = col >> 6, d = col & 63;
            long dst = ((long)(b * 8 + h)) * ((long)SEQ * HD) +
                       (long)qt * HD + d;
            bf16 h0 = (bf16)qv;
            Cb0[dst] = h0;
            Cb1[dst] = (bf16)(qv - (float)h0);
          } else if (n0 < 1024) {  // K
            int c2 = col - 512;
            int h = c2 >> 6, d = c2 & 63;
            long dst = ((long)(b * 8 + h)) * ((long)SEQ * HD) +
                       (long)qt * HD + d;
            bf16 h0 = (bf16)v;
            Cb2[dst] = h0;
            E0[dst] = (bf16)(v - (float)h0);
          } else {  // V^T: [bh][d][k], 128-row pad per bh untouched
            int c2 = col - 1024;
            int h = c2 >> 6, d = c2 & 63;
            long dst = ((long)(b * 8 + h)) * ((long)128 * SEQ) +
                       (long)d * SEQ + qt;
            bf16 h0 = (bf16)v;
            E1[dst] = h0;
            E2[dst] = (bf16)(v - (float)h0);
          }
          continue;
        }
        if (Cf) Cf[z * sCf + (long)row * N + col] = v;
        if (Cb0) {
          long cib = (outmode == 1)
                         ? ((long)(z >> 3) * ((long)SEQ * DIMD) +
                            (long)(z & 7) * HD + (long)row * DIMD + col)
                         : (z * sCb + (long)row * N + col);
          bf16 h0 = (bf16)v;
          Cb0[cib] = h0;
          if (Cb1) {
            float r = v - (float)h0;
            bf16 h1 = (bf16)r;
            Cb1[cib] = h1;
            if (Cb2) Cb2[cib] = (bf16)(r - (float)h1);
          }
        }
      }
    }
  }
}

// ====== dedicated head GEMM: BK=64, chunk-XOR swizzle, plain bf16 ======
__global__ __launch_bounds__(256) void k_hgemm(const bf16* __restrict__ A,
                                               const bf16* __restrict__ Bt,
                                               float* __restrict__ C,
                                               int M, int N, int K) {
  __shared__ __align__(16) bf16 As[128 * 64];
  __shared__ __align__(16) bf16 Bs[128 * 64];
  int tid = threadIdx.x;
  int nwg = gridDim.x * gridDim.y;
  int flat = blockIdx.y * gridDim.x + blockIdx.x;
  int qq = nwg >> 3, rr = nwg & 7;
  int xcd = flat & 7, ii = flat >> 3;
  int swz = (xcd < rr ? xcd * (qq + 1) : rr * (qq + 1) + (xcd - rr) * qq) + ii;
  int m0 = (swz % gridDim.x) * 128, n0 = (swz / gridDim.x) * 128;
  int w = tid >> 6, lane = tid & 63;
  int wm = (w >> 1) * 64, wn = (w & 1) * 64;
  int r15 = lane & 15, kg = lane >> 4;
  int srow = tid >> 3;  // 0..31
  int scol = (((tid & 7) ^ ((tid >> 3) & 7))) << 3;
  const bf16* ga = A + (long)(m0 + srow) * K + scol;
  const bf16* gb = Bt + (long)(n0 + srow) * K + scol;
  f32x4 acc[4][4] = {};
  for (int k0 = 0; k0 < K; k0 += 64) {
#pragma unroll
    for (int i = 0; i < 4; ++i) {
      gl_lds16(ga + (long)i * 32 * K + k0, &As[i * 2048 + tid * 8]);
      gl_lds16(gb + (long)i * 32 * K + k0, &Bs[i * 2048 + tid * 8]);
    }
    __syncthreads();  // tiles ready
#pragma unroll
    for (int kk = 0; kk < 2; ++kk) {
      bf16x8 af[4], bf_[4];
#pragma unroll
      for (int mi = 0; mi < 4; ++mi) {
        int rowA = wm + mi * 16 + r15;
        af[mi] = *(const bf16x8*)
            &As[rowA * 64 + ((((kk * 4 + kg) ^ (rowA & 7))) << 3)];
      }
#pragma unroll
      for (int ni = 0; ni < 4; ++ni) {
        int rowB = wn + ni * 16 + r15;
        bf_[ni] = *(const bf16x8*)
            &Bs[rowB * 64 + ((((kk * 4 + kg) ^ (rowB & 7))) << 3)];
      }
#pragma unroll
      for (int mi = 0; mi < 4; ++mi)
#pragma unroll
        for (int ni = 0; ni < 4; ++ni)
          acc[mi][ni] = __builtin_amdgcn_mfma_f32_16x16x32_bf16(
              af[mi], bf_[ni], acc[mi][ni], 0, 0, 0);
    }
    __syncthreads();  // reads done before overwrite
  }
#pragma unroll
  for (int mi = 0; mi < 4; ++mi) {
    int rbase = m0 + wm + mi * 16 + kg * 4;
#pragma unroll
    for (int ni = 0; ni < 4; ++ni) {
      int col = n0 + wn + ni * 16 + r15;
      if (col >= N) continue;
#pragma unroll
      for (int reg = 0; reg < 4; ++reg)
        C[(long)(rbase + reg) * N + col] = acc[mi][ni][reg];
    }
  }
}

// ---------------- helpers ----------------
__global__ __launch_bounds__(256) void k_embed(const int* __restrict__ ids,
                                               const float* __restrict__ E,
                                               float* __restrict__ xf,
                                               bf16* __restrict__ x0,
                                               bf16* __restrict__ x1) {
  int i = blockIdx.x * 256 + threadIdx.x;
  if (i >= NTOK * DIMD) return;
  int n = i >> 9, d = i & 511;
  float v = E[(long)ids[n] * DIMD + d];
  xf[i] = v;
  bf16 b0 = (bf16)v;
  x0[i] = b0;
  x1[i] = (bf16)(v - (float)b0);
}

// f32 -> 2-term bf16 split, 8 elems/thread
__global__ __launch_bounds__(256) void k_split2(const float* __restrict__ s,
                                                bf16* __restrict__ d0,
                                                bf16* __restrict__ d1, long n8) {
  long i = (long)blockIdx.x * 256 + threadIdx.x;
  if (i >= n8) return;
  const float4* s4 = (const float4*)s;
  float4 a = s4[2 * i], b = s4[2 * i + 1];
  float vv[8] = {a.x, a.y, a.z, a.w, b.x, b.y, b.z, b.w};
  bf16x8 o0, o1;
#pragma unroll
  for (int j = 0; j < 8; ++j) {
    float v = vv[j];
    bf16 h0 = (bf16)v;
    o0[j] = h0;
    o1[j] = (bf16)(v - (float)h0);
  }
  ((bf16x8*)d0)[i] = o0;
  ((bf16x8*)d1)[i] = o1;
}

__global__ __launch_bounds__(256) void k_headconv(const float* __restrict__ s,
                                                  bf16* __restrict__ d) {
  long i = (long)blockIdx.x * 256 + threadIdx.x;
  long n8 = (long)HROWS * DIMD / 8;
  if (i >= n8) return;
  long row = i / (DIMD / 8);
  bf16x8 o;
  if (row < VOCABN) {
    const float4* s4 = (const float4*)s;
    float4 a = s4[2 * i], b = s4[2 * i + 1];
    o[0] = (bf16)a.x; o[1] = (bf16)a.y; o[2] = (bf16)a.z; o[3] = (bf16)a.w;
    o[4] = (bf16)b.x; o[5] = (bf16)b.y; o[6] = (bf16)b.z; o[7] = (bf16)b.w;
  } else {
    o = (bf16x8)(bf16)0.f;
  }
  ((bf16x8*)d)[i] = o;
}

// in-place row softmax on 2-split bf16 scores [16*SEQ][SEQ] (vectorized)
__global__ __launch_bounds__(256) void k_softmax(bf16* __restrict__ p0,
                                                 bf16* __restrict__ p1) {
  int row = blockIdx.x;
  int t = threadIdx.x;
  long base = (long)row * SEQ;
  bf16x4 a0 = ((const bf16x4*)(p0 + base))[t];
  bf16x4 a1 = ((const bf16x4*)(p1 + base))[t];
  float v[4];
#pragma unroll
  for (int j = 0; j < 4; ++j) v[j] = (float)a0[j] + (float)a1[j];
  __shared__ float red[256];
  float m = fmaxf(fmaxf(v[0], v[1]), fmaxf(v[2], v[3]));
  red[t] = m;
  __syncthreads();
  for (int off = 128; off; off >>= 1) {
    if (t < off) red[t] = fmaxf(red[t], red[t + off]);
    __syncthreads();
  }
  m = red[0];
  __syncthreads();
  float s = 0.f;
#pragma unroll
  for (int j = 0; j < 4; ++j) {
    v[j] = __expf(v[j] - m);
    s += v[j];
  }
  red[t] = s;
  __syncthreads();
  for (int off = 128; off; off >>= 1) {
    if (t < off) red[t] += red[t + off];
    __syncthreads();
  }
  float inv = 1.f / red[0];
  bf16x4 o0, o1;
#pragma unroll
  for (int j = 0; j < 4; ++j) {
    float p = v[j] * inv;
    bf16 h0 = (bf16)p;
    o0[j] = h0;
    o1[j] = (bf16)(p - (float)h0);
  }
  ((bf16x4*)(p0 + base))[t] = o0;
  ((bf16x4*)(p1 + base))[t] = o1;
}

// router: top-2 expert ids + normalized weights per token
__global__ __launch_bounds__(64) void k_router(const float* __restrict__ x,
                                               const float* __restrict__ rw,
                                               const float* __restrict__ rb,
                                               int* __restrict__ top2,
                                               float* __restrict__ v2) {
  int n = blockIdx.x;
  int t = threadIdx.x;
  int e = t >> 3, part = t & 7;
  __shared__ float red[64];
  const float* xr = x + (long)n * DIMD;
  const float* wr = rw + (long)e * DIMD;
  float d = 0.f;
  int c0 = part * 64;
#pragma unroll
  for (int c = 0; c < 64; c += 4) {
    float4 xv = *(const float4*)(xr + c0 + c);
    float4 wv = *(const float4*)(wr + c0 + c);
    d += xv.x * wv.x + xv.y * wv.y + xv.z * wv.z + xv.w * wv.w;
  }
  red[t] = d;
  __syncthreads();
  if (t < 8) {
    float logit = rb[t];
    for (int pp = 0; pp < 8; ++pp) logit += red[t * 8 + pp];
    red[t] = logit;
  }
  __syncthreads();
  if (t == 0) {
    float p2[8];
    float m = -1e30f;
    for (int i = 0; i < 8; ++i) m = fmaxf(m, red[i]);
    float s = 0.f;
    for (int i = 0; i < 8; ++i) { p2[i] = expf(red[i] - m); s += p2[i]; }
    for (int i = 0; i < 8; ++i) p2[i] /= s;
    int i1 = 0;
    for (int i = 1; i < 8; ++i) if (p2[i] > p2[i1]) i1 = i;
    int i2 = (i1 == 0) ? 1 : 0;
    for (int i = 0; i < 8; ++i) {
      if (i == i1 || i == i2) continue;
      if (p2[i] > p2[i2]) i2 = i;
    }
    float sum = p2[i1] + p2[i2] + 1e-8f;
    top2[2 * n] = i1;
    top2[2 * n + 1] = i2;
    v2[2 * n] = p2[i1] / sum;
    v2[2 * n + 1] = p2[i2] / sum;
  }
}

// per-expert token lists, one-pass 8-elem/thread prefix scan (deterministic)
__global__ __launch_bounds__(256) void k_expcnt(const int* __restrict__ top2,
                                                int* __restrict__ perm,
                                                int* __restrict__ tokpos,
                                                int* __restrict__ cnt,
                                                bf16* __restrict__ zx0,
                                                bf16* __restrict__ zx1) {
  int e = blockIdx.x, t = threadIdx.x;
  if (e == 0) {
    for (int c = t; c < DIMD; c += 256) {
      zx0[c] = (bf16)0.f;
      zx1[c] = (bf16)0.f;
    }
  }
  __shared__ int sc[256];
  int fl[8];
  int f = 0;
#pragma unroll
  for (int j = 0; j < 8; ++j) {
    int n = t * 8 + j;
    int m = (top2[2 * n] == e || top2[2 * n + 1] == e) ? 1 : 0;
    fl[j] = m;
    f += m;
  }
  sc[t] = f;
  __syncthreads();
  for (int o = 1; o < 256; o <<= 1) {
    int v = (t >= o) ? sc[t - o] : 0;
    __syncthreads();
    sc[t] += v;
    __syncthreads();
  }
  int pos = sc[t] - f;  // exclusive prefix
#pragma unroll
  for (int j = 0; j < 8; ++j) {
    if (fl[j]) {
      int n = t * 8 + j;
      perm[e * 2048 + pos] = n;
      int jj = (top2[2 * n] == e) ? 0 : 1;
      tokpos[2 * n + jj] = e * 2048 + pos;
      ++pos;
    }
  }
  int total = sc[255];
  int cpad = (total + 127) & ~127;
  for (int i = total + t; i < cpad; i += 256) perm[e * 2048 + i] = 2048;
  if (t == 0) cnt[e] = total;
}

// BitNet: q in {-1,0,1} (exact bf16) + per-row f32 scale
__global__ __launch_bounds__(256) void k_bitw(const float* __restrict__ w,
                                              bf16* __restrict__ q,
                                              float* __restrict__ s, int cols) {
  int row = blockIdx.x;
  int t = threadIdx.x;
  const float* wr = w + (long)row * cols;
  float acc = 0.f;
  for (int c = t; c < cols; c += 256) acc += fabsf(wr[c]);
  __shared__ float red[256];
  red[t] = acc;
  __syncthreads();
  for (int off = 128; off; off >>= 1) {
    if (t < off) red[t] += red[t + off];
    __syncthreads();
  }
  float scale = fmaxf(red[0] / (float)cols, 1e-5f);
  if (t == 0) s[row] = scale;
  bf16* outr = q + (long)row * cols;
  for (int c = t; c < cols; c += 256) {
    float qv = rintf(wr[c] / scale);  // RNE, matches jnp.round
    qv = fmaxf(-1.f, fminf(1.f, qv));
    outr[c] = (bf16)qv;
  }
}

// combine top-2 experts (gathered f32 y), add residual, LN -> f32 + 2-split
__global__ __launch_bounds__(128) void k_lncomb(
    const float* __restrict__ yg, const int* __restrict__ tokpos,
    const float* __restrict__ v2, const float* __restrict__ xBf,
    const float* __restrict__ g, const float* __restrict__ b,
    float* __restrict__ xof, bf16* __restrict__ x0, bf16* __restrict__ x1) {
  int n = blockIdx.x;
  int t = threadIdx.x;
  __shared__ float red[128];
  long tp0 = tokpos[2 * n], tp1 = tokpos[2 * n + 1];
  float w0 = v2[2 * n], w1 = v2[2 * n + 1];
  const float* y0 = yg + tp0 * DIMD;
  const float* y1 = yg + tp1 * DIMD;
  float u[4];
  float s = 0.f;
#pragma unroll
  for (int i = 0; i < 4; ++i) {
    int d = t + i * 128;
    float v = xBf[(long)n * DIMD + d] + w0 * y0[d] + w1 * y1[d];
    u[i] = v;
    s += v;
  }
  red[t] = s;
  __syncthreads();
  for (int off = 64; off; off >>= 1) {
    if (t < off) red[t] += red[t + off];
    __syncthreads();
  }
  float mu = red[0] / (float)DIMD;
  __syncthreads();
  float var = 0.f;
#pragma unroll
  for (int i = 0; i < 4; ++i) {
    float d = u[i] - mu;
    var += d * d;
  }
  red[t] = var;
  __syncthreads();
  for (int off = 64; off; off >>= 1) {
    if (t < off) red[t] += red[t + off];
    __syncthreads();
  }
  float inv = 1.f / sqrtf(red[0] / (float)DIMD + 1e-5f);
#pragma unroll
  for (int i = 0; i < 4; ++i) {
    int c = t + i * 128;
    float v = (u[i] - mu) * inv * g[c] + b[c];
    long oi = (long)n * DIMD + c;
    xof[oi] = v;
    bf16 b0 = (bf16)v;
    x0[oi] = b0;
    x1[oi] = (bf16)(v - (float)b0);
  }
}

extern "C" void kernel_launch(void* const* d_in, const int* in_sizes, int n_in,
                              void* d_out, int out_size, void* d_ws, size_t ws_size,
                              hipStream_t stream) {
  const int* ids = (const int*)d_in[0];
  const float* embed = (const float*)d_in[1];
  const float* qkv_w = (const float*)d_in[2];
  const float* out_w = (const float*)d_in[3];
  const float* router_w = (const float*)d_in[4];
  const float* router_b = (const float*)d_in[5];
  const float* w1 = (const float*)d_in[6];
  const float* b1 = (const float*)d_in[7];
  const float* w2 = (const float*)d_in[8];
  const float* b2 = (const float*)d_in[9];
  const float* ln_g = (const float*)d_in[10];
  const float* ln_b = (const float*)d_in[11];
  const float* head_w = (const float*)d_in[12];
  float* out = (float*)d_out;

  char* base = (char*)d_ws;
  size_t off = 0;
  auto alloc = [&](size_t bytes) -> void* {
    void* p = base + off;
    off += (bytes + 255) & ~(size_t)255;
    return p;
  };
  const size_t ND = (size_t)NTOK * DIMD;
  float* xAf = (float*)alloc(ND * 4);
  float* xBf = (float*)alloc(ND * 4);
  int* top2 = (int*)alloc((size_t)NTOK * 2 * 4);
  float* v2 = (float*)alloc((size_t)NTOK * 2 * 4);
  int* perm = (int*)alloc((size_t)EXPERTS * 2048 * 4);
  int* tokpos = (int*)alloc((size_t)NTOK * 2 * 4);
  int* cntb = (int*)alloc(64);
  bf16* xA0 = (bf16*)alloc(ND * 2);
  bf16* xA1 = (bf16*)alloc(ND * 2);
  bf16* xB0 = (bf16*)alloc((ND + DIMD) * 2);  // +1 zero row (idx 2048)
  bf16* xB1 = (bf16*)alloc((ND + DIMD) * 2);
  bf16* at0 = (bf16*)alloc(ND * 2);
  bf16* at1 = (bf16*)alloc(ND * 2);
  bf16* qw0 = (bf16*)alloc((size_t)3 * DIMD * DIMD * 2);
  bf16* qw1 = (bf16*)alloc((size_t)3 * DIMD * DIMD * 2);
  bf16* ow0 = (bf16*)alloc((size_t)DIMD * DIMD * 2);
  bf16* ow1 = (bf16*)alloc((size_t)DIMD * DIMD * 2);
  bf16* q0b = (bf16*)alloc((size_t)16 * SEQ * HD * 2);
  bf16* q1b = (bf16*)alloc((size_t)16 * SEQ * HD * 2);
  bf16* k0b = (bf16*)alloc((size_t)16 * SEQ * HD * 2);
  bf16* k1b = (bf16*)alloc((size_t)16 * SEQ * HD * 2);
  bf16* vt0b = (bf16*)alloc((size_t)16 * 128 * SEQ * 2);  // 128 rows: pad
  bf16* vt1b = (bf16*)alloc((size_t)16 * 128 * SEQ * 2);

  // ---- union region (time-multiplexed; per-layer lifetimes disjoint) ----
  size_t Ustart = off;
  // layout A: 2-split attention scores/probs (offsets kept clear of layout B
  // regions that are live at the same time only across layer boundaries)
  bf16* p0b = (bf16*)(base + Ustart + ((size_t)64 << 20));
  bf16* p1b = (bf16*)(base + Ustart + ((size_t)96 << 20));
  size_t endA = Ustart + ((size_t)128 << 20);
  // layout B: expert scratch (gathered layouts, 2048 rows/expert stride)
  bf16* we1q = (bf16*)alloc((size_t)EXPERTS * FF * DIMD * 2);
  float* s1 = (float*)alloc((size_t)EXPERTS * FF * 4);
  bf16* we2q = (bf16*)alloc((size_t)EXPERTS * DIMD * FF * 2);
  float* s2 = (float*)alloc((size_t)EXPERTS * DIMD * 4);
  bf16* h0g = (bf16*)alloc((size_t)EXPERTS * 2048 * FF * 2);
  bf16* h1g = (bf16*)alloc((size_t)EXPERTS * 2048 * FF * 2);
  float* yg = (float*)alloc((size_t)EXPERTS * 2048 * DIMD * 4);
  size_t endB = off;
  // layout C: head weights
  size_t endC = Ustart + (size_t)HROWS * DIMD * 2;
  bf16* hw0 = (bf16*)(base + Ustart);
  off = endA > endB ? endA : endB;
  if (endC > off) off = endC;
  if (ws_size < off) return;

  k_embed<<<(NTOK * DIMD + 255) / 256, 256, 0, stream>>>(ids, embed, xAf, xA0,
                                                         xA1);

  for (int l = 0; l < NLAYER; ++l) {
    const float* qw = qkv_w + (long)l * 3 * DIMD * DIMD;
    const float* ow = out_w + (long)l * DIMD * DIMD;
    long nq8 = (long)3 * DIMD * DIMD / 8;
    long no8 = (long)DIMD * DIMD / 8;
    k_split2<<<(int)((nq8 + 255) / 256), 256, 0, stream>>>(qw, qw0, qw1, nq8);
    k_split2<<<(int)((no8 + 255) / 256), 256, 0, stream>>>(ow, ow0, ow1, no8);
    // fused qkv: x @ qkv_w^T -> q/k 2-splits + v^T 2-splits (mode 5)
    k_mfma_gemm<<<dim3(NTOK / 128, (3 * DIMD) / 128, 1), 256, 0, stream>>>(
        xA0, xA1, nullptr, qw0, qw1, nullptr, nullptr, q0b, q1b, k0b,
        k1b, vt0b, vt1b, NTOK, 3 * DIMD, DIMD, 0, 0, 0, 0,
        nullptr, 0, nullptr, 0, nullptr, 0, 5, nullptr, nullptr, 2);
    // scores = Q @ K^T -> 2-split bf16 [bh][q][k]  (mode 5)
    k_mfma_gemm<<<dim3(SEQ / 128, SEQ / 128, 16), 256, 0, stream>>>(
        q0b, q1b, nullptr, k0b, k1b, nullptr, nullptr, p0b, p1b, nullptr,
        nullptr, nullptr, nullptr, SEQ, SEQ, HD,
        (long)SEQ * HD, (long)SEQ * HD, 0, (long)SEQ * SEQ,
        nullptr, 0, nullptr, 0, nullptr, 0, 5, nullptr, nullptr, 0);
    k_softmax<<<16 * SEQ, 256, 0, stream>>>(p0b, p1b);
    // O = P @ V -> token-layout 2-split (mode 5, outmode 1)
    k_mfma_gemm<<<dim3(SEQ / 128, 1, 16), 256, 0, stream>>>(
        p0b, p1b, nullptr, vt0b, vt1b, nullptr, nullptr, at0, at1, nullptr,
        nullptr, nullptr, nullptr, SEQ, HD, SEQ,
        (long)SEQ * SEQ, (long)128 * SEQ, 0, 0,
        nullptr, 0, nullptr, 0, nullptr, 0, 5, nullptr, nullptr, 1);
    // xB = attn_o @ out_w^T + xA  (mode 5; f32 + 2-split out)
    k_mfma_gemm<<<dim3(NTOK / 128, DIMD / 128, 1), 256, 0, stream>>>(
        at0, at1, nullptr, ow0, ow1, nullptr, xBf, xB0, xB1, nullptr,
        nullptr, nullptr, nullptr, NTOK, DIMD, DIMD, 0, 0, 0, 0,
        nullptr, 0, nullptr, 0, xAf, 0, 5, nullptr, nullptr, 0);
    k_router<<<NTOK, 64, 0, stream>>>(xBf, router_w + (long)l * EXPERTS * DIMD,
                                      router_b + l * EXPERTS, top2, v2);
    k_expcnt<<<EXPERTS, 256, 0, stream>>>(top2, perm, tokpos, cntb,
                                          xB0 + ND, xB1 + ND);
    k_bitw<<<EXPERTS * FF, 256, 0, stream>>>(w1 + (long)l * EXPERTS * FF * DIMD,
                                             we1q, s1, DIMD);
    k_bitw<<<EXPERTS * DIMD, 256, 0, stream>>>(
        w2 + (long)l * EXPERTS * DIMD * FF, we2q, s2, FF);
    // h[e] = gelu((gather(xB) @ q1[e]^T)*s1 + b1)  (mode 3, sparse)
    k_mfma_gemm<<<dim3(NTOK / 128, FF / 128, EXPERTS), 256, 0, stream>>>(
        xB0, xB1, nullptr, we1q, nullptr, nullptr, nullptr, h0g, h1g, nullptr,
        nullptr, nullptr, nullptr, NTOK, FF, DIMD,
        0, (long)FF * DIMD, 0, (long)2048 * FF,
        s1, FF, b1 + (long)l * EXPERTS * FF, FF, nullptr, 1, 3, cntb, perm, 0);
    // y[e] = (h[e] @ q2[e]^T)*s2 + b2  (mode 3, sparse, f32 out)
    k_mfma_gemm<<<dim3(NTOK / 128, DIMD / 128, EXPERTS), 256, 0, stream>>>(
        h0g, h1g, nullptr, we2q, nullptr, nullptr, yg, nullptr, nullptr,
        nullptr, nullptr, nullptr, nullptr, NTOK, DIMD, FF,
        (long)2048 * FF, (long)DIMD * FF, (long)2048 * DIMD, 0,
        s2, DIMD, b2 + (long)l * EXPERTS * DIMD, DIMD,
        nullptr, 0, 3, cntb, nullptr, 0);
    k_lncomb<<<NTOK, 128, 0, stream>>>(yg, tokpos, v2, xBf, ln_g + l * DIMD,
                                       ln_b + l * DIMD, xAf, xA0, xA1);
  }
  // head: logits = x @ head_w^T  (dedicated BK=64 kernel)
  long nh8 = (long)HROWS * DIMD / 8;
  k_headconv<<<(int)((nh8 + 255) / 256), 256, 0, stream>>>(head_w, hw0);
  k_hgemm<<<dim3(NTOK / 128, HROWS / 128, 1), 256, 0, stream>>>(
      xA0, hw0, out, NTOK, VOCABN, DIMD);
}